// Round 17
// baseline (188.339 us; speedup 1.0000x reference)
//
#include <hip/hip_runtime.h>

// ---- problem geometry ----
#define D_MODEL 512
#define HD      1960
#define NPAD    2048          // HD padded to tile multiple
#define NVECS   720
#define MROWS   14400         // 4*3600
#define MPAD    14592         // 57*256 = 114*128
#define HP      66
#define WP      114
#define IMGPIX  7524          // HP*WP

typedef __bf16 bf16x8 __attribute__((ext_vector_type(8)));
typedef float  f32x4  __attribute__((ext_vector_type(4)));

__device__ __forceinline__ unsigned short f2bf(float f) {
    unsigned u = __builtin_bit_cast(unsigned, f);
    u += 0x7FFFu + ((u >> 16) & 1u);   // RNE
    return (unsigned short)(u >> 16);
}
__device__ __forceinline__ float bf2f(unsigned short s) {
    unsigned u = ((unsigned)s) << 16;
    return __builtin_bit_cast(float, u);
}

__device__ __forceinline__ void gload_lds16(const unsigned short* g, unsigned short* l) {
    __builtin_amdgcn_global_load_lds(
        (const __attribute__((address_space(1))) unsigned int*)g,
        (__attribute__((address_space(3))) unsigned int*)l,
        16, 0, 0);
}

// ---- convert x (fp32) -> bf16, zero-pad rows [14400,14592) ----
__global__ void cvt_x(const float* __restrict__ x, unsigned short* __restrict__ xb) {
    size_t i = ((size_t)blockIdx.x * 256 + threadIdx.x) * 4;
    const size_t valid = (size_t)MROWS * D_MODEL;
    if (i >= (size_t)MPAD * D_MODEL) return;
    ushort4 o;
    if (i < valid) {
        float4 v = *(const float4*)(x + i);
        o.x = f2bf(v.x); o.y = f2bf(v.y); o.z = f2bf(v.z); o.w = f2bf(v.w);
    } else {
        o.x = o.y = o.z = o.w = 0;
    }
    *(ushort4*)(xb + i) = o;
}

// ---- tiled transpose + fp32->bf16, zero-fill outside src ----
__global__ void transpose_cvt(const float* __restrict__ src, unsigned short* __restrict__ dst,
                              int srcR, int srcC, int dstR, int dstC) {
    __shared__ float tile[32][33];
    int c0 = blockIdx.x * 32;
    int r0 = blockIdx.y * 32;
    int tx = threadIdx.x, ty = threadIdx.y;   // (32,8)
    #pragma unroll
    for (int i = 0; i < 32; i += 8) {
        int sr = c0 + ty + i, sc = r0 + tx;
        tile[ty + i][tx] = (sr < srcR && sc < srcC) ? src[(size_t)sr * srcC + sc] : 0.f;
    }
    __syncthreads();
    #pragma unroll
    for (int i = 0; i < 32; i += 8) {
        int dr = r0 + ty + i, dc = c0 + tx;
        if (dr < dstR && dc < dstC)
            dst[(size_t)dr * dstC + dc] = f2bf(tile[tx][ty + i]);
    }
}

// ---- GEMM1: 256x256, m201-style 8-phase ring pipeline, bf16, transposed hT out ----
// 8 waves (wr=wid>>2 in 0..1, wc=wid&3 in 0..3), wave tile 128(m) x 64(n).
// LDS = 4 ring slots x 32KB; slot = half-K (32 k-elems): A 256rx32k (16KB) + B 256rx32k (16KB).
// Slot-XOR layout (R12-proven family): phys row p=r>>1 (128B rows of 8x16B chunks);
//   chunk (r&1)*4+kq stored at slot ((r&1)*4+kq)^(p&7).
// Ring: slot content hs consumed at its 2 phases; next content staged 3 slots ahead
//   (A-piece at even phase, B-piece at odd). Steady vmcnt(10) = 5 newer pieces x 2 instr.
__global__ __launch_bounds__(512, 2) void gemm8p(const unsigned short* __restrict__ A,
                        const unsigned short* __restrict__ BT,
                        const float* __restrict__ bias,
                        unsigned short* __restrict__ hT,
                        int K, int validN) {
    __shared__ unsigned short lds[4][16384];   // 128KB
    const int t    = threadIdx.x;
    const int lane = t & 63, wid = t >> 6;
    const int wr   = wid >> 2, wc = wid & 3;
    const int lr   = lane & 15, lh = lane >> 4;
    const int m0   = blockIdx.y * 256, n0 = blockIdx.x * 256;
    const int HS   = K >> 5;                   // half-K slots (16 for K=512)

    // staging per-thread constants: chunks c = t, t+512 of each 16KB piece
    int srcOff0, srcOff1;                      // element offset within panel row-block
    {
        int c = t, p = c >> 3, s = c & 7, lc = s ^ (p & 7);
        srcOff0 = (2 * p + (lc >> 2)) * K + (lc & 3) * 8;
        c = t + 512; p = c >> 3; s = c & 7; lc = s ^ (p & 7);
        srcOff1 = (2 * p + (lc >> 2)) * K + (lc & 3) * 8;
    }
    const unsigned short* Asrc0 = A  + (size_t)m0 * K + srcOff0;
    const unsigned short* Asrc1 = A  + (size_t)m0 * K + srcOff1;
    const unsigned short* Bsrc0 = BT + (size_t)n0 * K + srcOff0;
    const unsigned short* Bsrc1 = BT + (size_t)n0 * K + srcOff1;

#define STG_A(hs) do { int rs_ = (hs) & 3; \
        gload_lds16(Asrc0 + (hs) * 32, &lds[rs_][0] + t * 8); \
        gload_lds16(Asrc1 + (hs) * 32, &lds[rs_][0] + (t + 512) * 8); } while (0)
#define STG_B(hs) do { int rs_ = (hs) & 3; \
        gload_lds16(Bsrc0 + (hs) * 32, &lds[rs_][8192] + t * 8); \
        gload_lds16(Bsrc1 + (hs) * 32, &lds[rs_][8192] + (t + 512) * 8); } while (0)

    f32x4 acc[8][4] = {};

    STG_A(0); STG_B(0); STG_A(1); STG_B(1); STG_A(2); STG_B(2);

    for (int hs = 0; hs < HS; ++hs) {
        const int rs = hs & 3;
        const unsigned short* La = &lds[rs][0];
        const unsigned short* Lb = &lds[rs][8192];
        const int rem = HS - hs;
        // ---- EVEN phase: m-frags 0-3 ----
        if (rem > 3) { STG_A(hs + 3); asm volatile("s_waitcnt vmcnt(10)" ::: "memory"); }
        else if (rem == 3) asm volatile("s_waitcnt vmcnt(8)" ::: "memory");
        else if (rem == 2) asm volatile("s_waitcnt vmcnt(4)" ::: "memory");
        else               asm volatile("s_waitcnt vmcnt(0)" ::: "memory");
        __builtin_amdgcn_s_barrier();
        bf16x8 bfr[4], afr[4];
        #pragma unroll
        for (int g = 0; g < 4; ++g) {
            int r = wc * 64 + g * 16 + lr, p = r >> 1;
            bfr[g] = *(const bf16x8*)(Lb + p * 64 + (((((r & 1) << 2) | lh) ^ (p & 7)) * 8));
        }
        #pragma unroll
        for (int f = 0; f < 4; ++f) {
            int r = wr * 128 + f * 16 + lr, p = r >> 1;
            afr[f] = *(const bf16x8*)(La + p * 64 + (((((r & 1) << 2) | lh) ^ (p & 7)) * 8));
        }
        asm volatile("s_waitcnt lgkmcnt(0)" ::: "memory");
        __builtin_amdgcn_sched_barrier(0);
        __builtin_amdgcn_s_setprio(1);
        #pragma unroll
        for (int f = 0; f < 4; ++f)
            #pragma unroll
            for (int g = 0; g < 4; ++g)
                acc[f][g] = __builtin_amdgcn_mfma_f32_16x16x32_bf16(afr[f], bfr[g], acc[f][g], 0, 0, 0);
        __builtin_amdgcn_s_setprio(0);
        __builtin_amdgcn_s_barrier();
        // ---- ODD phase: m-frags 4-7 (reuse bfr) ----
        if (rem > 3) STG_B(hs + 3);
        __builtin_amdgcn_s_barrier();
        #pragma unroll
        for (int f = 0; f < 4; ++f) {
            int r = wr * 128 + (f + 4) * 16 + lr, p = r >> 1;
            afr[f] = *(const bf16x8*)(La + p * 64 + (((((r & 1) << 2) | lh) ^ (p & 7)) * 8));
        }
        asm volatile("s_waitcnt lgkmcnt(0)" ::: "memory");
        __builtin_amdgcn_sched_barrier(0);
        __builtin_amdgcn_s_setprio(1);
        #pragma unroll
        for (int f = 0; f < 4; ++f)
            #pragma unroll
            for (int g = 0; g < 4; ++g)
                acc[f + 4][g] = __builtin_amdgcn_mfma_f32_16x16x32_bf16(afr[f], bfr[g], acc[f + 4][g], 0, 0, 0);
        __builtin_amdgcn_s_setprio(0);
        __builtin_amdgcn_s_barrier();
    }
#undef STG_A
#undef STG_B

    // ---- epilogue (R10-refcheck'd): restage 256x256 bf16 C-tile, store hT col-major ----
    __syncthreads();
    unsigned short* sm = &lds[0][0];           // 65536 ushorts = 128KB
    #pragma unroll
    for (int f = 0; f < 8; ++f) {
        #pragma unroll
        for (int g = 0; g < 4; ++g) {
            int col = wc * 64 + g * 16 + lr;
            int gcol = n0 + col;
            float bv = (gcol < validN) ? bias[gcol] : 0.f;
            int gr = wr * 32 + f * 4 + lh;     // row granule (rows gr*4..gr*4+3)
            ushort4 v4;
            v4.x = f2bf(acc[f][g][0] + bv);
            v4.y = f2bf(acc[f][g][1] + bv);
            v4.z = f2bf(acc[f][g][2] + bv);
            v4.w = f2bf(acc[f][g][3] + bv);
            *(ushort4*)(sm + col * 256 + ((gr ^ (col & 63)) << 2)) = v4;
        }
    }
    __syncthreads();
    int col = t & 255, half = t >> 8;
    int gcol = n0 + col;
    if (gcol < validN) {
        #pragma unroll
        for (int i = 0; i < 32; ++i) {
            int gr = half * 32 + i;
            ushort4 v4 = *(const ushort4*)(sm + col * 256 + ((gr ^ (col & 63)) << 2));
            *(ushort4*)&hT[(size_t)gcol * MPAD + m0 + gr * 4] = v4;
        }
    }
}

// ---- 128x128 BK=64 double-buffered counted-vmcnt bf16 GEMM (R12-proven, GEMM2) ----
// MODE 1: out fp32 row-major (ldc=512), skip rows >= validM
template<int MODE>
__global__ __launch_bounds__(256) void gemm_bt(const unsigned short* __restrict__ A,
                        const unsigned short* __restrict__ BT,
                        const float* __restrict__ bias,
                        void* __restrict__ Cout,
                        int K, int ldc, int validN, int validM) {
    __shared__ unsigned short lds[2][16384];   // 64KB total
    const int t    = threadIdx.x;
    const int wid  = t >> 6, lane = t & 63;
    const int wr   = wid >> 1, wc = wid & 1;
    const int lr   = lane & 15, lh = lane >> 4;
    const int m0   = blockIdx.y * 128, n0 = blockIdx.x * 128;

    int rr[4], qq[4];
    #pragma unroll
    for (int i = 0; i < 4; ++i) {
        int c = t + i * 256;
        rr[i] = c >> 3;
        qq[i] = (c & 7) ^ (rr[i] & 7);
    }

#define STAGE(buf, kt) do { \
        unsigned short* LA = &lds[buf][0]; \
        unsigned short* LB = &lds[buf][8192]; \
        _Pragma("unroll") \
        for (int i = 0; i < 4; ++i) { \
            gload_lds16(A  + (size_t)(m0 + rr[i]) * K + (kt) + qq[i] * 8, LA + (t + i * 256) * 8); \
            gload_lds16(BT + (size_t)(n0 + rr[i]) * K + (kt) + qq[i] * 8, LB + (t + i * 256) * 8); \
        } \
    } while (0)

    f32x4 acc[4][4] = {};
    const int NT = K >> 6;

    STAGE(0, 0);
    for (int tt = 0; tt < NT; ++tt) {
        if (tt + 1 < NT) {
            STAGE((tt + 1) & 1, (tt + 1) * 64);
            asm volatile("s_waitcnt vmcnt(8)" ::: "memory");
        } else {
            asm volatile("s_waitcnt vmcnt(0)" ::: "memory");
        }
        __builtin_amdgcn_s_barrier();
        __builtin_amdgcn_sched_barrier(0);
        const unsigned short* La = &lds[tt & 1][0];
        const unsigned short* Lb = &lds[tt & 1][8192];
        #pragma unroll
        for (int ks = 0; ks < 2; ++ks) {
            bf16x8 a[4], b[4];
            #pragma unroll
            for (int f = 0; f < 4; ++f) {
                int row = wr * 64 + f * 16 + lr;
                int sl  = (ks * 4 + lh) ^ (lr & 7);
                a[f] = *(const bf16x8*)(La + row * 64 + sl * 8);
            }
            #pragma unroll
            for (int g = 0; g < 4; ++g) {
                int row = wc * 64 + g * 16 + lr;
                int sl  = (ks * 4 + lh) ^ (lr & 7);
                b[g] = *(const bf16x8*)(Lb + row * 64 + sl * 8);
            }
            __builtin_amdgcn_s_setprio(1);
            #pragma unroll
            for (int fm = 0; fm < 4; ++fm)
                #pragma unroll
                for (int fn = 0; fn < 4; ++fn)
                    acc[fm][fn] = __builtin_amdgcn_mfma_f32_16x16x32_bf16(
                        a[fm], b[fn], acc[fm][fn], 0, 0, 0);
            __builtin_amdgcn_s_setprio(0);
        }
        __builtin_amdgcn_s_barrier();
        __builtin_amdgcn_sched_barrier(0);
    }
#undef STAGE

    // C/D layout: col=lane&15, row=(lane>>4)*4+j
    #pragma unroll
    for (int fm = 0; fm < 4; ++fm) {
        #pragma unroll
        for (int fn = 0; fn < 4; ++fn) {
            int gcol = n0 + wc * 64 + fn * 16 + lr;
            float bv = bias[gcol];
            #pragma unroll
            for (int j = 0; j < 4; ++j) {
                int grow = m0 + wr * 64 + fm * 16 + lh * 4 + j;
                if (grow < validM)
                    ((float*)Cout)[(size_t)grow * ldc + gcol] = acc[fm][fn][j] + bv;
            }
        }
    }
}

// ---- fold + normalize + relu -> per-(b2,c) padded image (bf16) ----
__global__ void fold_norm(const unsigned short* __restrict__ hT, unsigned short* __restrict__ img2) {
    int y  = blockIdx.x;
    int g  = blockIdx.y;
    int b2 = g / 10, cg = g % 10;
    int c0 = cg * 4;
    int x  = threadIdx.x;
    if (x >= WP) return;
    float val[4] = {0.f, 0.f, 0.f, 0.f};
    if (y >= 3 && y < 63 && x >= 3 && x < 111) {
        int kiA[3], biA[3], nki = 0;
        for (int ki = y % 3; ki < 7; ki += 3) {
            int bi = (y - ki) / 3;
            if (y - ki >= 0 && bi < 20) { kiA[nki] = ki; biA[nki] = bi; ++nki; }
        }
        int kjA[3], bjA[3], nkj = 0;
        for (int kj = x % 3; kj < 7; kj += 3) {
            int bj = (x - kj) / 3;
            if (x - kj >= 0 && bj < 36) { kjA[nkj] = kj; bjA[nkj] = bj; ++nkj; }
        }
        float s[4] = {0.f, 0.f, 0.f, 0.f};
        for (int i = 0; i < nki; ++i) {
            for (int j = 0; j < nkj; ++j) {
                int row = b2 * NVECS + biA[i] * 36 + bjA[j];
                int colb = kiA[i] * 7 + kjA[j];
                #pragma unroll
                for (int q = 0; q < 4; ++q)
                    s[q] += bf2f(hT[(size_t)((c0 + q) * 49 + colb) * MPAD + row]);
            }
        }
        float inv = 1.f / (float)(nki * nkj);
        #pragma unroll
        for (int q = 0; q < 4; ++q)
            val[q] = fmaxf(s[q] * inv, 0.f);
    }
    #pragma unroll
    for (int q = 0; q < 4; ++q)
        img2[(size_t)(b2 * 40 + c0 + q) * IMGPIX + y * WP + x] = f2bf(val[q]);
}

// ---- unfold, LDS-staged ----
__global__ void unfold_k(const unsigned short* __restrict__ img2, unsigned short* __restrict__ h2b) {
    __shared__ unsigned short lds[20 * 798];
    __shared__ unsigned short lut[980];
    const int gb = blockIdx.x;                 // b2*20 + bi
    const int cg = blockIdx.y;
    const int b2 = gb / 20, bi = gb % 20;
    const int t  = threadIdx.x;

    const unsigned short* src = img2 + (size_t)(b2 * 40 + cg * 20) * IMGPIX + (bi * 3) * WP;
    for (int p = t; p < 7980; p += 256) {
        int cc = p / 399, rem2 = p - cc * 399;
        *(ushort2*)&lds[cc * 798 + rem2 * 2] =
            *(const ushort2*)&src[(size_t)cc * IMGPIX + rem2 * 2];
    }
    for (int L = t; L < 980; L += 256) {
        int cc = L / 49, kk = L - cc * 49;
        lut[L] = (unsigned short)(cc * 798 + (kk / 7) * 114 + (kk % 7));
    }
    __syncthreads();

    const int cpr   = (cg == 0) ? 245 : 267;
    const int total = 36 * cpr;
    const int rowbase = b2 * NVECS + bi * 36;
    const int hdbase  = cg * 980;
    for (int i = t; i < total; i += 256) {
        int r = i / cpr, q = i - r * cpr;
        int hl = q * 4;
        ushort4 v;
        unsigned short* vv = (unsigned short*)&v;
        #pragma unroll
        for (int e = 0; e < 4; ++e) {
            int h = hl + e;
            vv[e] = (h < 980) ? lds[lut[h] + r * 3] : (unsigned short)0;
        }
        *(ushort4*)&h2b[(size_t)(rowbase + r) * NPAD + hdbase + hl] = v;
    }
}

extern "C" void kernel_launch(void* const* d_in, const int* in_sizes, int n_in,
                              void* d_out, int out_size, void* d_ws, size_t ws_size,
                              hipStream_t stream) {
    const float* x  = (const float*)d_in[0];
    const float* W1 = (const float*)d_in[1];
    const float* b1 = (const float*)d_in[2];
    const float* W2 = (const float*)d_in[3];
    const float* b2 = (const float*)d_in[4];
    float* out = (float*)d_out;

    unsigned short* xb   = (unsigned short*)d_ws;                 // MPAD*512
    unsigned short* W1T  = xb   + (size_t)MPAD * D_MODEL;         // 2048*512
    unsigned short* W2T  = W1T  + (size_t)NPAD * D_MODEL;         // 512*2048
    unsigned short* hT   = W2T  + (size_t)D_MODEL * NPAD;         // NPAD*MPAD (transposed)
    unsigned short* h2b  = hT   + (size_t)NPAD * MPAD;            // MPAD*NPAD
    unsigned short* img2 = h2b  + (size_t)MPAD * NPAD;            // 800*7524

    cvt_x<<<(MPAD * D_MODEL / 4 + 255) / 256, 256, 0, stream>>>(x, xb);

    dim3 tb(32, 8);
    transpose_cvt<<<dim3(512 / 32, NPAD / 32), tb, 0, stream>>>(W1, W1T, D_MODEL, HD, NPAD, D_MODEL);
    transpose_cvt<<<dim3(NPAD / 32, 512 / 32), tb, 0, stream>>>(W2, W2T, HD, D_MODEL, D_MODEL, NPAD);

    // GEMM1: hT = (xb @ W1T^T + b1)^T, 256^2 8-phase ring pipeline, grid 8x57 = 456
    gemm8p<<<dim3(NPAD / 256, MPAD / 256), 512, 0, stream>>>(
        xb, W1T, b1, hT, D_MODEL, HD);

    fold_norm<<<dim3(HP, 200), 128, 0, stream>>>(hT, img2);
    unfold_k<<<dim3(400, 2), 256, 0, stream>>>(img2, h2b);

    // GEMM2: out = h2b @ W2T^T + b2  (fp32, rows<14400 only), grid 4x114 (R12 structure)
    gemm_bt<1><<<dim3(512 / 128, MPAD / 128), 256, 0, stream>>>(
        h2b, W2T, b2, out, NPAD, D_MODEL, D_MODEL, MROWS);
}

// Round 18
// 176.071 us; speedup vs baseline: 1.0697x; 1.0697x over previous
//
#include <hip/hip_runtime.h>

// ---- problem geometry ----
#define D_MODEL 512
#define HD      1960
#define NPAD    2048          // HD padded to tile multiple
#define NVECS   720
#define MROWS   14400         // 4*3600
#define MPAD    14464         // 113*128
#define HP      66
#define WP      114
#define IMGPIX  7524          // HP*WP

typedef __bf16 bf16x8 __attribute__((ext_vector_type(8)));
typedef float  f32x4  __attribute__((ext_vector_type(4)));

__device__ __forceinline__ unsigned short f2bf(float f) {
    unsigned u = __builtin_bit_cast(unsigned, f);
    u += 0x7FFFu + ((u >> 16) & 1u);   // RNE
    return (unsigned short)(u >> 16);
}
__device__ __forceinline__ float bf2f(unsigned short s) {
    unsigned u = ((unsigned)s) << 16;
    return __builtin_bit_cast(float, u);
}

__device__ __forceinline__ void gload_lds16(const unsigned short* g, unsigned short* l) {
    __builtin_amdgcn_global_load_lds(
        (const __attribute__((address_space(1))) unsigned int*)g,
        (__attribute__((address_space(3))) unsigned int*)l,
        16, 0, 0);
}

// ---- fused prep: z=0 cvt x->bf16 (pad rows); z=1 W1->W1T; z=2 W2->W2T ----
__global__ void prep(const float* __restrict__ x,  unsigned short* __restrict__ xb,
                     const float* __restrict__ W1, unsigned short* __restrict__ W1T,
                     const float* __restrict__ W2, unsigned short* __restrict__ W2T) {
    const int z = blockIdx.z;
    const int t = threadIdx.x;
    if (z == 0) {
        size_t i = ((size_t)blockIdx.x * 256 + t) * 4;
        const size_t valid = (size_t)MROWS * D_MODEL;
        if (i >= (size_t)MPAD * D_MODEL) return;
        ushort4 o;
        if (i < valid) {
            float4 v = *(const float4*)(x + i);
            o.x = f2bf(v.x); o.y = f2bf(v.y); o.z = f2bf(v.z); o.w = f2bf(v.w);
        } else {
            o.x = o.y = o.z = o.w = 0;
        }
        *(ushort4*)(xb + i) = o;
        return;
    }
    // tiled transpose + cvt (32x32 tiles, 256 threads as 32x8)
    __shared__ float tile[32][33];
    const int bid = blockIdx.x;
    if (bid >= 1024) return;                   // both transposes use 1024 tiles
    const int tx = t & 31, ty = t >> 5;
    const float* src; unsigned short* dst;
    int srcR, srcC, dstR, dstC, c0, r0;
    if (z == 1) {  // W1 (512x1960) -> W1T (2048x512): 16 col-tiles x 64 row-tiles
        src = W1; dst = W1T; srcR = 512; srcC = HD; dstR = NPAD; dstC = 512;
        c0 = (bid & 15) * 32; r0 = (bid >> 4) * 32;
    } else {       // W2 (1960x512) -> W2T (512x2048): 64 col-tiles x 16 row-tiles
        src = W2; dst = W2T; srcR = HD; srcC = 512; dstR = 512; dstC = NPAD;
        c0 = (bid & 63) * 32; r0 = (bid >> 6) * 32;
    }
    #pragma unroll
    for (int i = 0; i < 32; i += 8) {
        int sr = c0 + ty + i, sc = r0 + tx;
        tile[ty + i][tx] = (sr < srcR && sc < srcC) ? src[(size_t)sr * srcC + sc] : 0.f;
    }
    __syncthreads();
    #pragma unroll
    for (int i = 0; i < 32; i += 8) {
        int dr = r0 + ty + i, dc = c0 + tx;
        if (dr < dstR && dc < dstC)
            dst[(size_t)dr * dstC + dc] = f2bf(tile[tx][ty + i]);
    }
}

// ---- 128x128 BK=64 double-buffered counted-vmcnt bf16 GEMM (R12-proven) ----
// MODE 0: out bf16 TRANSPOSED  hT[col*MPAD + row], skip cols >= validN (GEMM1)
// MODE 1: out fp32 row-major (ldc=512), skip rows >= validM           (GEMM2)
template<int MODE>
__global__ __launch_bounds__(256) void gemm_bt(const unsigned short* __restrict__ A,
                        const unsigned short* __restrict__ BT,
                        const float* __restrict__ bias,
                        void* __restrict__ Cout,
                        int K, int ldc, int validN, int validM) {
    __shared__ unsigned short lds[2][16384];   // 64KB total
    const int t    = threadIdx.x;
    const int wid  = t >> 6, lane = t & 63;
    const int wr   = wid >> 1, wc = wid & 1;
    const int lr   = lane & 15, lh = lane >> 4;
    const int m0   = blockIdx.y * 128, n0 = blockIdx.x * 128;

    int rr[4], qq[4];
    #pragma unroll
    for (int i = 0; i < 4; ++i) {
        int c = t + i * 256;
        rr[i] = c >> 3;
        qq[i] = (c & 7) ^ (rr[i] & 7);
    }

#define STAGE(buf, kt) do { \
        unsigned short* LA = &lds[buf][0]; \
        unsigned short* LB = &lds[buf][8192]; \
        _Pragma("unroll") \
        for (int i = 0; i < 4; ++i) { \
            gload_lds16(A  + (size_t)(m0 + rr[i]) * K + (kt) + qq[i] * 8, LA + (t + i * 256) * 8); \
            gload_lds16(BT + (size_t)(n0 + rr[i]) * K + (kt) + qq[i] * 8, LB + (t + i * 256) * 8); \
        } \
    } while (0)

    f32x4 acc[4][4] = {};
    const int NT = K >> 6;

    STAGE(0, 0);
    for (int tt = 0; tt < NT; ++tt) {
        if (tt + 1 < NT) {
            STAGE((tt + 1) & 1, (tt + 1) * 64);
            asm volatile("s_waitcnt vmcnt(8)" ::: "memory");
        } else {
            asm volatile("s_waitcnt vmcnt(0)" ::: "memory");
        }
        __builtin_amdgcn_s_barrier();
        __builtin_amdgcn_sched_barrier(0);
        const unsigned short* La = &lds[tt & 1][0];
        const unsigned short* Lb = &lds[tt & 1][8192];
        #pragma unroll
        for (int ks = 0; ks < 2; ++ks) {
            bf16x8 a[4], b[4];
            #pragma unroll
            for (int f = 0; f < 4; ++f) {
                int row = wr * 64 + f * 16 + lr;
                int sl  = (ks * 4 + lh) ^ (lr & 7);
                a[f] = *(const bf16x8*)(La + row * 64 + sl * 8);
            }
            #pragma unroll
            for (int g = 0; g < 4; ++g) {
                int row = wc * 64 + g * 16 + lr;
                int sl  = (ks * 4 + lh) ^ (lr & 7);
                b[g] = *(const bf16x8*)(Lb + row * 64 + sl * 8);
            }
            __builtin_amdgcn_s_setprio(1);
            #pragma unroll
            for (int fm = 0; fm < 4; ++fm)
                #pragma unroll
                for (int fn = 0; fn < 4; ++fn)
                    acc[fm][fn] = __builtin_amdgcn_mfma_f32_16x16x32_bf16(
                        a[fm], b[fn], acc[fm][fn], 0, 0, 0);
            __builtin_amdgcn_s_setprio(0);
        }
        __builtin_amdgcn_s_barrier();
        __builtin_amdgcn_sched_barrier(0);
    }
#undef STAGE

    // C/D layout: col=lane&15, row=(lane>>4)*4+j  [m89 verified]
    if (MODE == 0) {
        unsigned short* smem = &lds[0][0];
        #pragma unroll
        for (int fm = 0; fm < 4; ++fm) {
            #pragma unroll
            for (int fn = 0; fn < 4; ++fn) {
                int lcol = wc * 64 + fn * 16 + lr;
                float bv = bias[n0 + lcol];
                #pragma unroll
                for (int j = 0; j < 4; ++j) {
                    int lrow = wr * 64 + fm * 16 + lh * 4 + j;
                    smem[lcol * 128 + (lrow ^ ((lcol & 15) << 3))] =
                        f2bf(acc[fm][fn][j] + bv);
                }
            }
        }
        __syncthreads();
        unsigned short* hT = (unsigned short*)Cout;
        int col = t >> 1, half = t & 1;
        int gcol = n0 + col;
        if (gcol < validN) {
            #pragma unroll
            for (int r = 0; r < 16; ++r) {
                int row = half * 64 + r * 4;
                ushort4 v4 = *(const ushort4*)&smem[col * 128 + (row ^ ((col & 15) << 3))];
                *(ushort4*)&hT[(size_t)gcol * MPAD + m0 + row] = v4;
            }
        }
    } else {
        #pragma unroll
        for (int fm = 0; fm < 4; ++fm) {
            #pragma unroll
            for (int fn = 0; fn < 4; ++fn) {
                int gcol = n0 + wc * 64 + fn * 16 + lr;
                float bv = bias[gcol];
                #pragma unroll
                for (int j = 0; j < 4; ++j) {
                    int grow = m0 + wr * 64 + fm * 16 + lh * 4 + j;
                    if (grow < validM)
                        ((float*)Cout)[(size_t)grow * ldc + gcol] = acc[fm][fn][j] + bv;
                }
            }
        }
    }
}

// ---- fold + normalize + relu -> per-(b2,c) padded image (bf16) ----
// grid (HP, 100), block 128: y=blockIdx.x, blockIdx.y = b2*5+cg (8 channels/thread).
__global__ void fold_norm(const unsigned short* __restrict__ hT, unsigned short* __restrict__ img2) {
    int y  = blockIdx.x;
    int g  = blockIdx.y;
    int b2 = g / 5, cg = g % 5;
    int c0 = cg * 8;
    int x  = threadIdx.x;
    if (x >= WP) return;
    float val[8] = {};
    if (y >= 3 && y < 63 && x >= 3 && x < 111) {
        int kiA[3], biA[3], nki = 0;
        for (int ki = y % 3; ki < 7; ki += 3) {
            int bi = (y - ki) / 3;
            if (y - ki >= 0 && bi < 20) { kiA[nki] = ki; biA[nki] = bi; ++nki; }
        }
        int kjA[3], bjA[3], nkj = 0;
        for (int kj = x % 3; kj < 7; kj += 3) {
            int bj = (x - kj) / 3;
            if (x - kj >= 0 && bj < 36) { kjA[nkj] = kj; bjA[nkj] = bj; ++nkj; }
        }
        float s[8] = {};
        for (int i = 0; i < nki; ++i) {
            for (int j = 0; j < nkj; ++j) {
                int row = b2 * NVECS + biA[i] * 36 + bjA[j];
                int colb = kiA[i] * 7 + kjA[j];
                #pragma unroll
                for (int q = 0; q < 8; ++q)
                    s[q] += bf2f(hT[(size_t)((c0 + q) * 49 + colb) * MPAD + row]);
            }
        }
        float inv = 1.f / (float)(nki * nkj);
        #pragma unroll
        for (int q = 0; q < 8; ++q)
            val[q] = fmaxf(s[q] * inv, 0.f);
    }
    #pragma unroll
    for (int q = 0; q < 8; ++q)
        img2[(size_t)(b2 * 40 + c0 + q) * IMGPIX + y * WP + x] = f2bf(val[q]);
}

// ---- unfold, LDS-staged: block (b2*20+bi, cg). Stage img2 slab, write h2b coalesced. ----
// h2b pad rows [14400,14464) left unwritten: only feed GEMM2 output rows >= validM (never stored).
__global__ void unfold_k(const unsigned short* __restrict__ img2, unsigned short* __restrict__ h2b) {
    __shared__ unsigned short lds[20 * 798];
    __shared__ unsigned short lut[980];
    const int gb = blockIdx.x;                 // b2*20 + bi
    const int cg = blockIdx.y;
    const int b2 = gb / 20, bi = gb % 20;
    const int t  = threadIdx.x;

    const unsigned short* src = img2 + (size_t)(b2 * 40 + cg * 20) * IMGPIX + (bi * 3) * WP;
    for (int p = t; p < 7980; p += 256) {
        int cc = p / 399, rem2 = p - cc * 399;
        *(ushort2*)&lds[cc * 798 + rem2 * 2] =
            *(const ushort2*)&src[(size_t)cc * IMGPIX + rem2 * 2];
    }
    for (int L = t; L < 980; L += 256) {
        int cc = L / 49, kk = L - cc * 49;
        lut[L] = (unsigned short)(cc * 798 + (kk / 7) * 114 + (kk % 7));
    }
    __syncthreads();

    const int cpr   = (cg == 0) ? 245 : 267;
    const int total = 36 * cpr;
    const int rowbase = b2 * NVECS + bi * 36;
    const int hdbase  = cg * 980;
    for (int i = t; i < total; i += 256) {
        int r = i / cpr, q = i - r * cpr;
        int hl = q * 4;
        ushort4 v;
        unsigned short* vv = (unsigned short*)&v;
        #pragma unroll
        for (int e = 0; e < 4; ++e) {
            int h = hl + e;
            vv[e] = (h < 980) ? lds[lut[h] + r * 3] : (unsigned short)0;
        }
        *(ushort4*)&h2b[(size_t)(rowbase + r) * NPAD + hdbase + hl] = v;
    }
}

extern "C" void kernel_launch(void* const* d_in, const int* in_sizes, int n_in,
                              void* d_out, int out_size, void* d_ws, size_t ws_size,
                              hipStream_t stream) {
    const float* x  = (const float*)d_in[0];
    const float* W1 = (const float*)d_in[1];
    const float* b1 = (const float*)d_in[2];
    const float* W2 = (const float*)d_in[3];
    const float* b2 = (const float*)d_in[4];
    float* out = (float*)d_out;

    unsigned short* xb   = (unsigned short*)d_ws;                 // MPAD*512
    unsigned short* W1T  = xb   + (size_t)MPAD * D_MODEL;         // 2048*512
    unsigned short* W2T  = W1T  + (size_t)NPAD * D_MODEL;         // 512*2048
    unsigned short* hT   = W2T  + (size_t)D_MODEL * NPAD;         // NPAD*MPAD (transposed)
    unsigned short* h2b  = hT   + (size_t)NPAD * MPAD;            // MPAD*NPAD
    unsigned short* img2 = h2b  + (size_t)MPAD * NPAD;            // 800*7524

    // fused prep: z=0 cvt (7232 blocks used), z=1/2 transposes (1024 blocks used)
    prep<<<dim3((MPAD * D_MODEL / 4 + 255) / 256, 1, 3), 256, 0, stream>>>(
        x, xb, W1, W1T, W2, W2T);

    // GEMM1: hT = (xb @ W1T^T + b1)^T   (bf16, transposed out), grid 16x113
    gemm_bt<0><<<dim3(NPAD / 128, MPAD / 128), 256, 0, stream>>>(
        xb, W1T, b1, hT, D_MODEL, 0, HD, MPAD);

    fold_norm<<<dim3(HP, 100), 128, 0, stream>>>(hT, img2);
    unfold_k<<<dim3(400, 2), 256, 0, stream>>>(img2, h2b);

    // GEMM2: out = h2b @ W2T^T + b2  (fp32, rows<14400 only), grid 4x113
    gemm_bt<1><<<dim3(512 / 128, MPAD / 128), 256, 0, stream>>>(
        h2b, W2T, b2, out, NPAD, D_MODEL, D_MODEL, MROWS);
}

// Round 20
// 174.964 us; speedup vs baseline: 1.0764x; 1.0063x over previous
//
#include <hip/hip_runtime.h>

// ---- problem geometry ----
#define D_MODEL 512
#define HD      1960
#define NPAD    2048          // HD padded to tile multiple
#define KEFF2   1984          // GEMM2 K loop bound: 31*64 (cols 1960..1983 are zero-filled)
#define NVECS   720
#define MROWS   14400         // 4*3600
#define MPAD    14464         // 113*128
#define HP      66
#define WP      114
#define IMGPIX  7524          // HP*WP

typedef __bf16 bf16x8 __attribute__((ext_vector_type(8)));
typedef float  f32x4  __attribute__((ext_vector_type(4)));

__device__ __forceinline__ unsigned short f2bf(float f) {
    unsigned u = __builtin_bit_cast(unsigned, f);
    u += 0x7FFFu + ((u >> 16) & 1u);   // RNE
    return (unsigned short)(u >> 16);
}
__device__ __forceinline__ float bf2f(unsigned short s) {
    unsigned u = ((unsigned)s) << 16;
    return __builtin_bit_cast(float, u);
}

__device__ __forceinline__ void gload_lds16(const unsigned short* g, unsigned short* l) {
    __builtin_amdgcn_global_load_lds(
        (const __attribute__((address_space(1))) unsigned int*)g,
        (__attribute__((address_space(3))) unsigned int*)l,
        16, 0, 0);
}

// ---- fused prep: z=0 cvt x->bf16 (pad rows); z=1 W1->W1T; z=2 W2->W2T ----
__global__ void prep(const float* __restrict__ x,  unsigned short* __restrict__ xb,
                     const float* __restrict__ W1, unsigned short* __restrict__ W1T,
                     const float* __restrict__ W2, unsigned short* __restrict__ W2T) {
    const int z = blockIdx.z;
    const int t = threadIdx.x;
    if (z == 0) {
        size_t i = ((size_t)blockIdx.x * 256 + t) * 4;
        const size_t valid = (size_t)MROWS * D_MODEL;
        if (i >= (size_t)MPAD * D_MODEL) return;
        ushort4 o;
        if (i < valid) {
            float4 v = *(const float4*)(x + i);
            o.x = f2bf(v.x); o.y = f2bf(v.y); o.z = f2bf(v.z); o.w = f2bf(v.w);
        } else {
            o.x = o.y = o.z = o.w = 0;
        }
        *(ushort4*)(xb + i) = o;
        return;
    }
    // tiled transpose + cvt (32x32 tiles, 256 threads as 32x8)
    __shared__ float tile[32][33];
    const int bid = blockIdx.x;
    if (bid >= 1024) return;                   // both transposes use 1024 tiles
    const int tx = t & 31, ty = t >> 5;
    const float* src; unsigned short* dst;
    int srcR, srcC, dstR, dstC, c0, r0;
    if (z == 1) {  // W1 (512x1960) -> W1T (2048x512): 16 col-tiles x 64 row-tiles
        src = W1; dst = W1T; srcR = 512; srcC = HD; dstR = NPAD; dstC = 512;
        c0 = (bid & 15) * 32; r0 = (bid >> 4) * 32;
    } else {       // W2 (1960x512) -> W2T (512x2048): 64 col-tiles x 16 row-tiles
        src = W2; dst = W2T; srcR = HD; srcC = 512; dstR = 512; dstC = NPAD;
        c0 = (bid & 63) * 32; r0 = (bid >> 6) * 32;
    }
    #pragma unroll
    for (int i = 0; i < 32; i += 8) {
        int sr = c0 + ty + i, sc = r0 + tx;
        tile[ty + i][tx] = (sr < srcR && sc < srcC) ? src[(size_t)sr * srcC + sc] : 0.f;
    }
    __syncthreads();
    #pragma unroll
    for (int i = 0; i < 32; i += 8) {
        int dr = r0 + ty + i, dc = c0 + tx;
        if (dr < dstR && dc < dstC)
            dst[(size_t)dr * dstC + dc] = f2bf(tile[tx][ty + i]);
    }
}

// ---- 128x128 BK=64 double-buffered counted-vmcnt bf16 GEMM (R12-proven) ----
// lda = row stride of A and BT; K = loop bound (K <= lda allowed, tail cols must be zero).
// MODE 0: out bf16 TRANSPOSED  hT[col*MPAD + row], skip cols >= validN (GEMM1)
// MODE 1: out fp32 row-major (ldc=512), skip rows >= validM           (GEMM2)
template<int MODE>
__global__ __launch_bounds__(256) void gemm_bt(const unsigned short* __restrict__ A,
                        const unsigned short* __restrict__ BT,
                        const float* __restrict__ bias,
                        void* __restrict__ Cout,
                        int K, int lda, int ldc, int validN, int validM) {
    __shared__ unsigned short lds[2][16384];   // 64KB total
    const int t    = threadIdx.x;
    const int wid  = t >> 6, lane = t & 63;
    const int wr   = wid >> 1, wc = wid & 1;
    const int lr   = lane & 15, lh = lane >> 4;
    const int m0   = blockIdx.y * 128, n0 = blockIdx.x * 128;

    int rr[4], qq[4];
    #pragma unroll
    for (int i = 0; i < 4; ++i) {
        int c = t + i * 256;
        rr[i] = c >> 3;
        qq[i] = (c & 7) ^ (rr[i] & 7);
    }

#define STAGE(buf, kt) do { \
        unsigned short* LA = &lds[buf][0]; \
        unsigned short* LB = &lds[buf][8192]; \
        _Pragma("unroll") \
        for (int i = 0; i < 4; ++i) { \
            gload_lds16(A  + (size_t)(m0 + rr[i]) * lda + (kt) + qq[i] * 8, LA + (t + i * 256) * 8); \
            gload_lds16(BT + (size_t)(n0 + rr[i]) * lda + (kt) + qq[i] * 8, LB + (t + i * 256) * 8); \
        } \
    } while (0)

    f32x4 acc[4][4] = {};
    const int NT = K >> 6;

    STAGE(0, 0);
    for (int tt = 0; tt < NT; ++tt) {
        if (tt + 1 < NT) {
            STAGE((tt + 1) & 1, (tt + 1) * 64);
            asm volatile("s_waitcnt vmcnt(8)" ::: "memory");
        } else {
            asm volatile("s_waitcnt vmcnt(0)" ::: "memory");
        }
        __builtin_amdgcn_s_barrier();
        __builtin_amdgcn_sched_barrier(0);
        const unsigned short* La = &lds[tt & 1][0];
        const unsigned short* Lb = &lds[tt & 1][8192];
        #pragma unroll
        for (int ks = 0; ks < 2; ++ks) {
            bf16x8 a[4], b[4];
            #pragma unroll
            for (int f = 0; f < 4; ++f) {
                int row = wr * 64 + f * 16 + lr;
                int sl  = (ks * 4 + lh) ^ (lr & 7);
                a[f] = *(const bf16x8*)(La + row * 64 + sl * 8);
            }
            #pragma unroll
            for (int g = 0; g < 4; ++g) {
                int row = wc * 64 + g * 16 + lr;
                int sl  = (ks * 4 + lh) ^ (lr & 7);
                b[g] = *(const bf16x8*)(Lb + row * 64 + sl * 8);
            }
            __builtin_amdgcn_s_setprio(1);
            #pragma unroll
            for (int fm = 0; fm < 4; ++fm)
                #pragma unroll
                for (int fn = 0; fn < 4; ++fn)
                    acc[fm][fn] = __builtin_amdgcn_mfma_f32_16x16x32_bf16(
                        a[fm], b[fn], acc[fm][fn], 0, 0, 0);
            __builtin_amdgcn_s_setprio(0);
        }
        __builtin_amdgcn_s_barrier();
        __builtin_amdgcn_sched_barrier(0);
    }
#undef STAGE

    // C/D layout: col=lane&15, row=(lane>>4)*4+j  [m89 verified]
    if (MODE == 0) {
        unsigned short* smem = &lds[0][0];
        #pragma unroll
        for (int fm = 0; fm < 4; ++fm) {
            #pragma unroll
            for (int fn = 0; fn < 4; ++fn) {
                int lcol = wc * 64 + fn * 16 + lr;
                float bv = bias[n0 + lcol];
                #pragma unroll
                for (int j = 0; j < 4; ++j) {
                    int lrow = wr * 64 + fm * 16 + lh * 4 + j;
                    smem[lcol * 128 + (lrow ^ ((lcol & 15) << 3))] =
                        f2bf(acc[fm][fn][j] + bv);
                }
            }
        }
        __syncthreads();
        unsigned short* hT = (unsigned short*)Cout;
        int col = t >> 1, half = t & 1;
        int gcol = n0 + col;
        if (gcol < validN) {
            #pragma unroll
            for (int r = 0; r < 16; ++r) {
                int row = half * 64 + r * 4;
                ushort4 v4 = *(const ushort4*)&smem[col * 128 + (row ^ ((col & 15) << 3))];
                *(ushort4*)&hT[(size_t)gcol * MPAD + m0 + row] = v4;
            }
        }
    } else {
        #pragma unroll
        for (int fm = 0; fm < 4; ++fm) {
            #pragma unroll
            for (int fn = 0; fn < 4; ++fn) {
                int gcol = n0 + wc * 64 + fn * 16 + lr;
                float bv = bias[gcol];
                #pragma unroll
                for (int j = 0; j < 4; ++j) {
                    int grow = m0 + wr * 64 + fm * 16 + lh * 4 + j;
                    if (grow < validM)
                        ((float*)Cout)[(size_t)grow * ldc + gcol] = acc[fm][fn][j] + bv;
                }
            }
        }
    }
}

// ---- fold + normalize + relu -> per-(b2,c) padded image (bf16) ----
// grid (HP, 100), block 128: y=blockIdx.x, blockIdx.y = b2*5+cg (8 channels/thread).
__global__ void fold_norm(const unsigned short* __restrict__ hT, unsigned short* __restrict__ img2) {
    int y  = blockIdx.x;
    int g  = blockIdx.y;
    int b2 = g / 5, cg = g % 5;
    int c0 = cg * 8;
    int x  = threadIdx.x;
    if (x >= WP) return;
    float val[8] = {};
    if (y >= 3 && y < 63 && x >= 3 && x < 111) {
        int kiA[3], biA[3], nki = 0;
        for (int ki = y % 3; ki < 7; ki += 3) {
            int bi = (y - ki) / 3;
            if (y - ki >= 0 && bi < 20) { kiA[nki] = ki; biA[nki] = bi; ++nki; }
        }
        int kjA[3], bjA[3], nkj = 0;
        for (int kj = x % 3; kj < 7; kj += 3) {
            int bj = (x - kj) / 3;
            if (x - kj >= 0 && bj < 36) { kjA[nkj] = kj; bjA[nkj] = bj; ++nkj; }
        }
        float s[8] = {};
        for (int i = 0; i < nki; ++i) {
            for (int j = 0; j < nkj; ++j) {
                int row = b2 * NVECS + biA[i] * 36 + bjA[j];
                int colb = kiA[i] * 7 + kjA[j];
                #pragma unroll
                for (int q = 0; q < 8; ++q)
                    s[q] += bf2f(hT[(size_t)((c0 + q) * 49 + colb) * MPAD + row]);
            }
        }
        float inv = 1.f / (float)(nki * nkj);
        #pragma unroll
        for (int q = 0; q < 8; ++q)
            val[q] = fmaxf(s[q] * inv, 0.f);
    }
    #pragma unroll
    for (int q = 0; q < 8; ++q)
        img2[(size_t)(b2 * 40 + c0 + q) * IMGPIX + y * WP + x] = f2bf(val[q]);
}

// ---- unfold, LDS-staged: block (b2*20+bi, cg). Stage img2 slab, write h2b coalesced. ----
// h2b pad rows [14400,14464) left unwritten: only feed GEMM2 output rows >= validM (never stored).
__global__ void unfold_k(const unsigned short* __restrict__ img2, unsigned short* __restrict__ h2b) {
    __shared__ unsigned short lds[20 * 798];
    __shared__ unsigned short lut[980];
    const int gb = blockIdx.x;                 // b2*20 + bi
    const int cg = blockIdx.y;
    const int b2 = gb / 20, bi = gb % 20;
    const int t  = threadIdx.x;

    const unsigned short* src = img2 + (size_t)(b2 * 40 + cg * 20) * IMGPIX + (bi * 3) * WP;
    for (int p = t; p < 7980; p += 256) {
        int cc = p / 399, rem2 = p - cc * 399;
        *(ushort2*)&lds[cc * 798 + rem2 * 2] =
            *(const ushort2*)&src[(size_t)cc * IMGPIX + rem2 * 2];
    }
    for (int L = t; L < 980; L += 256) {
        int cc = L / 49, kk = L - cc * 49;
        lut[L] = (unsigned short)(cc * 798 + (kk / 7) * 114 + (kk % 7));
    }
    __syncthreads();

    const int cpr   = (cg == 0) ? 245 : 267;
    const int total = 36 * cpr;
    const int rowbase = b2 * NVECS + bi * 36;
    const int hdbase  = cg * 980;
    for (int i = t; i < total; i += 256) {
        int r = i / cpr, q = i - r * cpr;
        int hl = q * 4;
        ushort4 v;
        unsigned short* vv = (unsigned short*)&v;
        #pragma unroll
        for (int e = 0; e < 4; ++e) {
            int h = hl + e;
            vv[e] = (h < 980) ? lds[lut[h] + r * 3] : (unsigned short)0;
        }
        *(ushort4*)&h2b[(size_t)(rowbase + r) * NPAD + hdbase + hl] = v;
    }
}

extern "C" void kernel_launch(void* const* d_in, const int* in_sizes, int n_in,
                              void* d_out, int out_size, void* d_ws, size_t ws_size,
                              hipStream_t stream) {
    const float* x  = (const float*)d_in[0];
    const float* W1 = (const float*)d_in[1];
    const float* b1 = (const float*)d_in[2];
    const float* W2 = (const float*)d_in[3];
    const float* b2 = (const float*)d_in[4];
    float* out = (float*)d_out;

    unsigned short* xb   = (unsigned short*)d_ws;                 // MPAD*512
    unsigned short* W1T  = xb   + (size_t)MPAD * D_MODEL;         // 2048*512
    unsigned short* W2T  = W1T  + (size_t)NPAD * D_MODEL;         // 512*2048
    unsigned short* hT   = W2T  + (size_t)D_MODEL * NPAD;         // NPAD*MPAD (transposed)
    unsigned short* h2b  = hT   + (size_t)NPAD * MPAD;            // MPAD*NPAD
    unsigned short* img2 = h2b  + (size_t)MPAD * NPAD;            // 800*7524

    // fused prep: z=0 cvt (7232 blocks used), z=1/2 transposes (1024 blocks used)
    prep<<<dim3((MPAD * D_MODEL / 4 + 255) / 256, 1, 3), 256, 0, stream>>>(
        x, xb, W1, W1T, W2, W2T);

    // GEMM1: hT = (xb @ W1T^T + b1)^T   (bf16, transposed out), grid 16x113
    gemm_bt<0><<<dim3(NPAD / 128, MPAD / 128), 256, 0, stream>>>(
        xb, W1T, b1, hT, D_MODEL, D_MODEL, 0, HD, MPAD);

    fold_norm<<<dim3(HP, 100), 128, 0, stream>>>(hT, img2);
    unfold_k<<<dim3(400, 2), 256, 0, stream>>>(img2, h2b);

    // GEMM2: out = h2b @ W2T^T + b2  (fp32, rows<14400 only), grid 4x113
    // K loop trimmed to 1984 (31 tiles); cols 1960..1983 are zeros in both h2b and W2T.
    gemm_bt<1><<<dim3(512 / 128, MPAD / 128), 256, 0, stream>>>(
        h2b, W2T, b2, out, KEFF2, NPAD, D_MODEL, D_MODEL, MROWS);
}

// Round 21
// 168.254 us; speedup vs baseline: 1.1194x; 1.0399x over previous
//
#include <hip/hip_runtime.h>

// ---- problem geometry ----
#define D_MODEL 512
#define HD      1960
#define NPAD    2048          // HD padded to tile multiple
#define KEFF2   1984          // GEMM2 K loop bound: 31*64 (cols 1960..1983 zero-filled)
#define NVECS   720
#define MROWS   14400         // 4*3600
#define MPAD    14464         // 113*128
#define HP      66
#define WP      114
#define IMGPIX  7524          // HP*WP

typedef __bf16 bf16x8 __attribute__((ext_vector_type(8)));
typedef float  f32x4  __attribute__((ext_vector_type(4)));

__device__ __forceinline__ unsigned short f2bf(float f) {
    unsigned u = __builtin_bit_cast(unsigned, f);
    u += 0x7FFFu + ((u >> 16) & 1u);   // RNE
    return (unsigned short)(u >> 16);
}
__device__ __forceinline__ float bf2f(unsigned short s) {
    unsigned u = ((unsigned)s) << 16;
    return __builtin_bit_cast(float, u);
}

__device__ __forceinline__ void gload_lds16(const unsigned short* g, unsigned short* l) {
    __builtin_amdgcn_global_load_lds(
        (const __attribute__((address_space(1))) unsigned int*)g,
        (__attribute__((address_space(3))) unsigned int*)l,
        16, 0, 0);
}

// ---- fused prep: z=0 cvt x->bf16 (pad rows); z=1 W1->W1T; z=2 W2->W2T ----
__global__ void prep(const float* __restrict__ x,  unsigned short* __restrict__ xb,
                     const float* __restrict__ W1, unsigned short* __restrict__ W1T,
                     const float* __restrict__ W2, unsigned short* __restrict__ W2T) {
    const int z = blockIdx.z;
    const int t = threadIdx.x;
    if (z == 0) {
        size_t i = ((size_t)blockIdx.x * 256 + t) * 4;
        const size_t valid = (size_t)MROWS * D_MODEL;
        if (i >= (size_t)MPAD * D_MODEL) return;
        ushort4 o;
        if (i < valid) {
            float4 v = *(const float4*)(x + i);
            o.x = f2bf(v.x); o.y = f2bf(v.y); o.z = f2bf(v.z); o.w = f2bf(v.w);
        } else {
            o.x = o.y = o.z = o.w = 0;
        }
        *(ushort4*)(xb + i) = o;
        return;
    }
    __shared__ float tile[32][33];
    const int bid = blockIdx.x;
    if (bid >= 1024) return;
    const int tx = t & 31, ty = t >> 5;
    const float* src; unsigned short* dst;
    int srcR, srcC, dstR, dstC, c0, r0;
    if (z == 1) {  // W1 (512x1960) -> W1T (2048x512)
        src = W1; dst = W1T; srcR = 512; srcC = HD; dstR = NPAD; dstC = 512;
        c0 = (bid & 15) * 32; r0 = (bid >> 4) * 32;
    } else {       // W2 (1960x512) -> W2T (512x2048)
        src = W2; dst = W2T; srcR = HD; srcC = 512; dstR = 512; dstC = NPAD;
        c0 = (bid & 63) * 32; r0 = (bid >> 6) * 32;
    }
    #pragma unroll
    for (int i = 0; i < 32; i += 8) {
        int sr = c0 + ty + i, sc = r0 + tx;
        tile[ty + i][tx] = (sr < srcR && sc < srcC) ? src[(size_t)sr * srcC + sc] : 0.f;
    }
    __syncthreads();
    #pragma unroll
    for (int i = 0; i < 32; i += 8) {
        int dr = r0 + ty + i, dc = c0 + tx;
        if (dr < dstR && dc < dstC)
            dst[(size_t)dr * dstC + dc] = f2bf(tile[tx][ty + i]);
    }
}

// ---- 128x128 BK=64 dbuf counted-vmcnt bf16 GEMM, 8 waves (4 waves/SIMD TLP) ----
// Wave grid: wr = wid>>1 (0..3, m), wc = wid&1 (0..1, n); wave tile 32(m) x 64(n), acc 2x4.
// LDS 64KB = 2 bufs x [A 16KB | B 16KB], slot-XOR (chunk kq at slot kq^(row&7)).
// Staging: 4 loads/thread/tile -> steady vmcnt(4), never 0 in-loop.
// lda = row stride; K = loop bound (K <= lda; tail cols must be zero).
// MODE 0: out bf16 TRANSPOSED hT[col*MPAD+row], skip cols >= validN (GEMM1)
// MODE 1: out fp32 row-major (ldc=512), skip rows >= validM          (GEMM2)
template<int MODE>
__global__ __launch_bounds__(512) void gemm_bt(const unsigned short* __restrict__ A,
                        const unsigned short* __restrict__ BT,
                        const float* __restrict__ bias,
                        void* __restrict__ Cout,
                        int K, int lda, int ldc, int validN, int validM) {
    __shared__ unsigned short lds[2][16384];   // 64KB total
    const int t    = threadIdx.x;
    const int wid  = t >> 6, lane = t & 63;
    const int wr   = wid >> 1, wc = wid & 1;
    const int lr   = lane & 15, lh = lane >> 4;
    const int m0   = blockIdx.y * 128, n0 = blockIdx.x * 128;

    // staging chunk map: 1024 chunks per matrix tile; thread owns c = t, t+512
    int rr[2], qq[2];
    #pragma unroll
    for (int i = 0; i < 2; ++i) {
        int c = t + i * 512;
        rr[i] = c >> 3;
        qq[i] = (c & 7) ^ (rr[i] & 7);
    }

#define STAGE(buf, kt) do { \
        unsigned short* LA = &lds[buf][0]; \
        unsigned short* LB = &lds[buf][8192]; \
        _Pragma("unroll") \
        for (int i = 0; i < 2; ++i) { \
            gload_lds16(A  + (size_t)(m0 + rr[i]) * lda + (kt) + qq[i] * 8, LA + (t + i * 512) * 8); \
            gload_lds16(BT + (size_t)(n0 + rr[i]) * lda + (kt) + qq[i] * 8, LB + (t + i * 512) * 8); \
        } \
    } while (0)

    f32x4 acc[2][4] = {};
    const int NT = K >> 6;

    STAGE(0, 0);
    for (int tt = 0; tt < NT; ++tt) {
        if (tt + 1 < NT) {
            STAGE((tt + 1) & 1, (tt + 1) * 64);
            asm volatile("s_waitcnt vmcnt(4)" ::: "memory");
        } else {
            asm volatile("s_waitcnt vmcnt(0)" ::: "memory");
        }
        __builtin_amdgcn_s_barrier();
        __builtin_amdgcn_sched_barrier(0);
        const unsigned short* La = &lds[tt & 1][0];
        const unsigned short* Lb = &lds[tt & 1][8192];
        #pragma unroll
        for (int ks = 0; ks < 2; ++ks) {
            bf16x8 a[2], b[4];
            #pragma unroll
            for (int f = 0; f < 2; ++f) {
                int row = wr * 32 + f * 16 + lr;       // row&7 == lr&7
                int sl  = (ks * 4 + lh) ^ (lr & 7);
                a[f] = *(const bf16x8*)(La + row * 64 + sl * 8);
            }
            #pragma unroll
            for (int g = 0; g < 4; ++g) {
                int row = wc * 64 + g * 16 + lr;
                int sl  = (ks * 4 + lh) ^ (lr & 7);
                b[g] = *(const bf16x8*)(Lb + row * 64 + sl * 8);
            }
            __builtin_amdgcn_s_setprio(1);
            #pragma unroll
            for (int fm = 0; fm < 2; ++fm)
                #pragma unroll
                for (int fn = 0; fn < 4; ++fn)
                    acc[fm][fn] = __builtin_amdgcn_mfma_f32_16x16x32_bf16(
                        a[fm], b[fn], acc[fm][fn], 0, 0, 0);
            __builtin_amdgcn_s_setprio(0);
        }
        __builtin_amdgcn_s_barrier();
        __builtin_amdgcn_sched_barrier(0);
    }
#undef STAGE

    // C/D layout: col=lane&15, row=(lane>>4)*4+j  [m89 verified]
    if (MODE == 0) {
        unsigned short* smem = &lds[0][0];   // 16384 ushorts = 32KB
        #pragma unroll
        for (int fm = 0; fm < 2; ++fm) {
            #pragma unroll
            for (int fn = 0; fn < 4; ++fn) {
                int lcol = wc * 64 + fn * 16 + lr;
                float bv = bias[n0 + lcol];
                #pragma unroll
                for (int j = 0; j < 4; ++j) {
                    int lrow = wr * 32 + fm * 16 + lh * 4 + j;
                    smem[lcol * 128 + (lrow ^ ((lcol & 15) << 3))] =
                        f2bf(acc[fm][fn][j] + bv);
                }
            }
        }
        __syncthreads();
        unsigned short* hT = (unsigned short*)Cout;
        int col = t >> 2, q = t & 3;     // 4 threads per column, 8 ushort4 each
        int gcol = n0 + col;
        if (gcol < validN) {
            #pragma unroll
            for (int r = 0; r < 8; ++r) {
                int row = q * 32 + r * 4;
                ushort4 v4 = *(const ushort4*)&smem[col * 128 + (row ^ ((col & 15) << 3))];
                *(ushort4*)&hT[(size_t)gcol * MPAD + m0 + row] = v4;
            }
        }
    } else {
        #pragma unroll
        for (int fm = 0; fm < 2; ++fm) {
            #pragma unroll
            for (int fn = 0; fn < 4; ++fn) {
                int gcol = n0 + wc * 64 + fn * 16 + lr;
                float bv = bias[gcol];
                #pragma unroll
                for (int j = 0; j < 4; ++j) {
                    int grow = m0 + wr * 32 + fm * 16 + lh * 4 + j;
                    if (grow < validM)
                        ((float*)Cout)[(size_t)grow * ldc + gcol] = acc[fm][fn][j] + bv;
                }
            }
        }
    }
}

// ---- fold + normalize + relu -> per-(b2,c) padded image (bf16), 8 ch/thread ----
__global__ void fold_norm(const unsigned short* __restrict__ hT, unsigned short* __restrict__ img2) {
    int y  = blockIdx.x;
    int g  = blockIdx.y;
    int b2 = g / 5, cg = g % 5;
    int c0 = cg * 8;
    int x  = threadIdx.x;
    if (x >= WP) return;
    float val[8] = {};
    if (y >= 3 && y < 63 && x >= 3 && x < 111) {
        int kiA[3], biA[3], nki = 0;
        for (int ki = y % 3; ki < 7; ki += 3) {
            int bi = (y - ki) / 3;
            if (y - ki >= 0 && bi < 20) { kiA[nki] = ki; biA[nki] = bi; ++nki; }
        }
        int kjA[3], bjA[3], nkj = 0;
        for (int kj = x % 3; kj < 7; kj += 3) {
            int bj = (x - kj) / 3;
            if (x - kj >= 0 && bj < 36) { kjA[nkj] = kj; bjA[nkj] = bj; ++nkj; }
        }
        float s[8] = {};
        for (int i = 0; i < nki; ++i) {
            for (int j = 0; j < nkj; ++j) {
                int row = b2 * NVECS + biA[i] * 36 + bjA[j];
                int colb = kiA[i] * 7 + kjA[j];
                #pragma unroll
                for (int q = 0; q < 8; ++q)
                    s[q] += bf2f(hT[(size_t)((c0 + q) * 49 + colb) * MPAD + row]);
            }
        }
        float inv = 1.f / (float)(nki * nkj);
        #pragma unroll
        for (int q = 0; q < 8; ++q)
            val[q] = fmaxf(s[q] * inv, 0.f);
    }
    #pragma unroll
    for (int q = 0; q < 8; ++q)
        img2[(size_t)(b2 * 40 + c0 + q) * IMGPIX + y * WP + x] = f2bf(val[q]);
}

// ---- unfold, LDS-staged ----
__global__ void unfold_k(const unsigned short* __restrict__ img2, unsigned short* __restrict__ h2b) {
    __shared__ unsigned short lds[20 * 798];
    __shared__ unsigned short lut[980];
    const int gb = blockIdx.x;                 // b2*20 + bi
    const int cg = blockIdx.y;
    const int b2 = gb / 20, bi = gb % 20;
    const int t  = threadIdx.x;

    const unsigned short* src = img2 + (size_t)(b2 * 40 + cg * 20) * IMGPIX + (bi * 3) * WP;
    for (int p = t; p < 7980; p += 256) {
        int cc = p / 399, rem2 = p - cc * 399;
        *(ushort2*)&lds[cc * 798 + rem2 * 2] =
            *(const ushort2*)&src[(size_t)cc * IMGPIX + rem2 * 2];
    }
    for (int L = t; L < 980; L += 256) {
        int cc = L / 49, kk = L - cc * 49;
        lut[L] = (unsigned short)(cc * 798 + (kk / 7) * 114 + (kk % 7));
    }
    __syncthreads();

    const int cpr   = (cg == 0) ? 245 : 267;
    const int total = 36 * cpr;
    const int rowbase = b2 * NVECS + bi * 36;
    const int hdbase  = cg * 980;
    for (int i = t; i < total; i += 256) {
        int r = i / cpr, q = i - r * cpr;
        int hl = q * 4;
        ushort4 v;
        unsigned short* vv = (unsigned short*)&v;
        #pragma unroll
        for (int e = 0; e < 4; ++e) {
            int h = hl + e;
            vv[e] = (h < 980) ? lds[lut[h] + r * 3] : (unsigned short)0;
        }
        *(ushort4*)&h2b[(size_t)(rowbase + r) * NPAD + hdbase + hl] = v;
    }
}

extern "C" void kernel_launch(void* const* d_in, const int* in_sizes, int n_in,
                              void* d_out, int out_size, void* d_ws, size_t ws_size,
                              hipStream_t stream) {
    const float* x  = (const float*)d_in[0];
    const float* W1 = (const float*)d_in[1];
    const float* b1 = (const float*)d_in[2];
    const float* W2 = (const float*)d_in[3];
    const float* b2 = (const float*)d_in[4];
    float* out = (float*)d_out;

    unsigned short* xb   = (unsigned short*)d_ws;                 // MPAD*512
    unsigned short* W1T  = xb   + (size_t)MPAD * D_MODEL;         // 2048*512
    unsigned short* W2T  = W1T  + (size_t)NPAD * D_MODEL;         // 512*2048
    unsigned short* hT   = W2T  + (size_t)D_MODEL * NPAD;         // NPAD*MPAD (transposed)
    unsigned short* h2b  = hT   + (size_t)NPAD * MPAD;            // MPAD*NPAD
    unsigned short* img2 = h2b  + (size_t)MPAD * NPAD;            // 800*7524

    prep<<<dim3((MPAD * D_MODEL / 4 + 255) / 256, 1, 3), 256, 0, stream>>>(
        x, xb, W1, W1T, W2, W2T);

    // GEMM1: hT = (xb @ W1T^T + b1)^T   (bf16, transposed out), grid 16x113, 512 thr
    gemm_bt<0><<<dim3(NPAD / 128, MPAD / 128), 512, 0, stream>>>(
        xb, W1T, b1, hT, D_MODEL, D_MODEL, 0, HD, MPAD);

    fold_norm<<<dim3(HP, 100), 128, 0, stream>>>(hT, img2);
    unfold_k<<<dim3(400, 2), 256, 0, stream>>>(img2, h2b);

    // GEMM2: out = h2b @ W2T^T + b2  (fp32, rows<14400), grid 4x113, 512 thr, K=1984
    gemm_bt<1><<<dim3(512 / 128, MPAD / 128), 512, 0, stream>>>(
        h2b, W2T, b2, out, KEFF2, NPAD, D_MODEL, D_MODEL, MROWS);
}

// Round 22
// 165.066 us; speedup vs baseline: 1.1410x; 1.0193x over previous
//
#include <hip/hip_runtime.h>

// ---- problem geometry ----
#define D_MODEL 512
#define HD      1960
#define NPAD    2048          // HD padded to tile multiple
#define KEFF2   1984          // GEMM2 K loop bound: 31*64 (cols 1960..1983 zero-filled)
#define NVECS   720
#define MROWS   14400         // 4*3600
#define MPAD    14464         // 113*128
#define HP      66
#define WP      114
#define IMGPIX  7524          // HP*WP

typedef __bf16 bf16x8 __attribute__((ext_vector_type(8)));
typedef float  f32x4  __attribute__((ext_vector_type(4)));

__device__ __forceinline__ unsigned short f2bf(float f) {
    unsigned u = __builtin_bit_cast(unsigned, f);
    u += 0x7FFFu + ((u >> 16) & 1u);   // RNE
    return (unsigned short)(u >> 16);
}
__device__ __forceinline__ float bf2f(unsigned short s) {
    unsigned u = ((unsigned)s) << 16;
    return __builtin_bit_cast(float, u);
}

__device__ __forceinline__ void gload_lds16(const unsigned short* g, unsigned short* l) {
    __builtin_amdgcn_global_load_lds(
        (const __attribute__((address_space(1))) unsigned int*)g,
        (__attribute__((address_space(3))) unsigned int*)l,
        16, 0, 0);
}

// ---- fused prep: z=0 cvt x->bf16 (pad rows); z=1 W1->W1T; z=2 W2->W2T ----
__global__ void prep(const float* __restrict__ x,  unsigned short* __restrict__ xb,
                     const float* __restrict__ W1, unsigned short* __restrict__ W1T,
                     const float* __restrict__ W2, unsigned short* __restrict__ W2T) {
    const int z = blockIdx.z;
    const int t = threadIdx.x;
    if (z == 0) {
        size_t i = ((size_t)blockIdx.x * 256 + t) * 4;
        const size_t valid = (size_t)MROWS * D_MODEL;
        if (i >= (size_t)MPAD * D_MODEL) return;
        ushort4 o;
        if (i < valid) {
            float4 v = *(const float4*)(x + i);
            o.x = f2bf(v.x); o.y = f2bf(v.y); o.z = f2bf(v.z); o.w = f2bf(v.w);
        } else {
            o.x = o.y = o.z = o.w = 0;
        }
        *(ushort4*)(xb + i) = o;
        return;
    }
    __shared__ float tile[32][33];
    const int bid = blockIdx.x;
    if (bid >= 1024) return;
    const int tx = t & 31, ty = t >> 5;
    const float* src; unsigned short* dst;
    int srcR, srcC, dstR, dstC, c0, r0;
    if (z == 1) {  // W1 (512x1960) -> W1T (2048x512)
        src = W1; dst = W1T; srcR = 512; srcC = HD; dstR = NPAD; dstC = 512;
        c0 = (bid & 15) * 32; r0 = (bid >> 4) * 32;
    } else {       // W2 (1960x512) -> W2T (512x2048)
        src = W2; dst = W2T; srcR = HD; srcC = 512; dstR = 512; dstC = NPAD;
        c0 = (bid & 63) * 32; r0 = (bid >> 6) * 32;
    }
    #pragma unroll
    for (int i = 0; i < 32; i += 8) {
        int sr = c0 + ty + i, sc = r0 + tx;
        tile[ty + i][tx] = (sr < srcR && sc < srcC) ? src[(size_t)sr * srcC + sc] : 0.f;
    }
    __syncthreads();
    #pragma unroll
    for (int i = 0; i < 32; i += 8) {
        int dr = r0 + ty + i, dc = c0 + tx;
        if (dr < dstR && dc < dstC)
            dst[(size_t)dr * dstC + dc] = f2bf(tile[tx][ty + i]);
    }
}

// ---- 128x128 BK=64 dbuf counted-vmcnt bf16 GEMM, 16 waves (8 waves/SIMD = max TLP) ----
// Wave grid: wr = wid>>1 (0..7, m), wc = wid&1 (0..1, n); wave tile 16(m) x 64(n), acc 1x4.
// LDS 64KB = 2 bufs x [A 16KB | B 16KB], slot-XOR (chunk kq at slot kq^(row&7)).
// Staging: 2 loads/thread/tile -> steady vmcnt(2), never 0 in-loop.
// lda = row stride; K = loop bound (K <= lda; tail cols must be zero).
// MODE 0: out bf16 TRANSPOSED hT[col*MPAD+row], skip cols >= validN (GEMM1)
// MODE 1: out fp32 row-major (ldc=512), skip rows >= validM          (GEMM2)
template<int MODE>
__global__ __launch_bounds__(1024, 8) void gemm_bt(const unsigned short* __restrict__ A,
                        const unsigned short* __restrict__ BT,
                        const float* __restrict__ bias,
                        void* __restrict__ Cout,
                        int K, int lda, int ldc, int validN, int validM) {
    __shared__ unsigned short lds[2][16384];   // 64KB total
    const int t    = threadIdx.x;
    const int wid  = t >> 6, lane = t & 63;
    const int wr   = wid >> 1, wc = wid & 1;
    const int lr   = lane & 15, lh = lane >> 4;
    const int m0   = blockIdx.y * 128, n0 = blockIdx.x * 128;

    // staging chunk map: 1024 chunks per matrix tile; thread owns chunk t of each
    const int rr = t >> 3;
    const int qq = (t & 7) ^ (rr & 7);

#define STAGE(buf, kt) do { \
        gload_lds16(A  + (size_t)(m0 + rr) * lda + (kt) + qq * 8, &lds[buf][0]    + t * 8); \
        gload_lds16(BT + (size_t)(n0 + rr) * lda + (kt) + qq * 8, &lds[buf][8192] + t * 8); \
    } while (0)

    f32x4 acc[4] = {};
    const int NT = K >> 6;

    STAGE(0, 0);
    for (int tt = 0; tt < NT; ++tt) {
        if (tt + 1 < NT) {
            STAGE((tt + 1) & 1, (tt + 1) * 64);
            asm volatile("s_waitcnt vmcnt(2)" ::: "memory");
        } else {
            asm volatile("s_waitcnt vmcnt(0)" ::: "memory");
        }
        __builtin_amdgcn_s_barrier();
        __builtin_amdgcn_sched_barrier(0);
        const unsigned short* La = &lds[tt & 1][0];
        const unsigned short* Lb = &lds[tt & 1][8192];
        #pragma unroll
        for (int ks = 0; ks < 2; ++ks) {
            const int sl = (ks * 4 + lh) ^ (lr & 7);
            bf16x8 a, b[4];
            {
                int row = wr * 16 + lr;               // row&7 == lr&7
                a = *(const bf16x8*)(La + row * 64 + sl * 8);
            }
            #pragma unroll
            for (int g = 0; g < 4; ++g) {
                int row = wc * 64 + g * 16 + lr;
                b[g] = *(const bf16x8*)(Lb + row * 64 + sl * 8);
            }
            __builtin_amdgcn_s_setprio(1);
            #pragma unroll
            for (int fn = 0; fn < 4; ++fn)
                acc[fn] = __builtin_amdgcn_mfma_f32_16x16x32_bf16(a, b[fn], acc[fn], 0, 0, 0);
            __builtin_amdgcn_s_setprio(0);
        }
        __builtin_amdgcn_s_barrier();
        __builtin_amdgcn_sched_barrier(0);
    }
#undef STAGE

    // C/D layout: col=lane&15, row=(lane>>4)*4+j  [m89 verified]
    if (MODE == 0) {
        unsigned short* smem = &lds[0][0];   // 16384 ushorts = 32KB
        #pragma unroll
        for (int fn = 0; fn < 4; ++fn) {
            int lcol = wc * 64 + fn * 16 + lr;
            float bv = bias[n0 + lcol];
            #pragma unroll
            for (int j = 0; j < 4; ++j) {
                int lrow = wr * 16 + lh * 4 + j;
                smem[lcol * 128 + (lrow ^ ((lcol & 15) << 3))] =
                    f2bf(acc[fn][j] + bv);
            }
        }
        __syncthreads();
        unsigned short* hT = (unsigned short*)Cout;
        int col = t >> 3, q = t & 7;     // 8 threads per column, 4 ushort4 each
        int gcol = n0 + col;
        if (gcol < validN) {
            #pragma unroll
            for (int r = 0; r < 4; ++r) {
                int row = q * 16 + r * 4;
                ushort4 v4 = *(const ushort4*)&smem[col * 128 + (row ^ ((col & 15) << 3))];
                *(ushort4*)&hT[(size_t)gcol * MPAD + m0 + row] = v4;
            }
        }
    } else {
        #pragma unroll
        for (int fn = 0; fn < 4; ++fn) {
            int gcol = n0 + wc * 64 + fn * 16 + lr;
            float bv = bias[gcol];
            #pragma unroll
            for (int j = 0; j < 4; ++j) {
                int grow = m0 + wr * 16 + lh * 4 + j;
                if (grow < validM)
                    ((float*)Cout)[(size_t)grow * ldc + gcol] = acc[fn][j] + bv;
            }
        }
    }
}

// ---- fold + normalize + relu -> per-(b2,c) padded image (bf16), 8 ch/thread ----
__global__ void fold_norm(const unsigned short* __restrict__ hT, unsigned short* __restrict__ img2) {
    int y  = blockIdx.x;
    int g  = blockIdx.y;
    int b2 = g / 5, cg = g % 5;
    int c0 = cg * 8;
    int x  = threadIdx.x;
    if (x >= WP) return;
    float val[8] = {};
    if (y >= 3 && y < 63 && x >= 3 && x < 111) {
        int kiA[3], biA[3], nki = 0;
        for (int ki = y % 3; ki < 7; ki += 3) {
            int bi = (y - ki) / 3;
            if (y - ki >= 0 && bi < 20) { kiA[nki] = ki; biA[nki] = bi; ++nki; }
        }
        int kjA[3], bjA[3], nkj = 0;
        for (int kj = x % 3; kj < 7; kj += 3) {
            int bj = (x - kj) / 3;
            if (x - kj >= 0 && bj < 36) { kjA[nkj] = kj; bjA[nkj] = bj; ++nkj; }
        }
        float s[8] = {};
        for (int i = 0; i < nki; ++i) {
            for (int j = 0; j < nkj; ++j) {
                int row = b2 * NVECS + biA[i] * 36 + bjA[j];
                int colb = kiA[i] * 7 + kjA[j];
                #pragma unroll
                for (int q = 0; q < 8; ++q)
                    s[q] += bf2f(hT[(size_t)((c0 + q) * 49 + colb) * MPAD + row]);
            }
        }
        float inv = 1.f / (float)(nki * nkj);
        #pragma unroll
        for (int q = 0; q < 8; ++q)
            val[q] = fmaxf(s[q] * inv, 0.f);
    }
    #pragma unroll
    for (int q = 0; q < 8; ++q)
        img2[(size_t)(b2 * 40 + c0 + q) * IMGPIX + y * WP + x] = f2bf(val[q]);
}

// ---- unfold, LDS-staged ----
__global__ void unfold_k(const unsigned short* __restrict__ img2, unsigned short* __restrict__ h2b) {
    __shared__ unsigned short lds[20 * 798];
    __shared__ unsigned short lut[980];
    const int gb = blockIdx.x;                 // b2*20 + bi
    const int cg = blockIdx.y;
    const int b2 = gb / 20, bi = gb % 20;
    const int t  = threadIdx.x;

    const unsigned short* src = img2 + (size_t)(b2 * 40 + cg * 20) * IMGPIX + (bi * 3) * WP;
    for (int p = t; p < 7980; p += 256) {
        int cc = p / 399, rem2 = p - cc * 399;
        *(ushort2*)&lds[cc * 798 + rem2 * 2] =
            *(const ushort2*)&src[(size_t)cc * IMGPIX + rem2 * 2];
    }
    for (int L = t; L < 980; L += 256) {
        int cc = L / 49, kk = L - cc * 49;
        lut[L] = (unsigned short)(cc * 798 + (kk / 7) * 114 + (kk % 7));
    }
    __syncthreads();

    const int cpr   = (cg == 0) ? 245 : 267;
    const int total = 36 * cpr;
    const int rowbase = b2 * NVECS + bi * 36;
    const int hdbase  = cg * 980;
    for (int i = t; i < total; i += 256) {
        int r = i / cpr, q = i - r * cpr;
        int hl = q * 4;
        ushort4 v;
        unsigned short* vv = (unsigned short*)&v;
        #pragma unroll
        for (int e = 0; e < 4; ++e) {
            int h = hl + e;
            vv[e] = (h < 980) ? lds[lut[h] + r * 3] : (unsigned short)0;
        }
        *(ushort4*)&h2b[(size_t)(rowbase + r) * NPAD + hdbase + hl] = v;
    }
}

extern "C" void kernel_launch(void* const* d_in, const int* in_sizes, int n_in,
                              void* d_out, int out_size, void* d_ws, size_t ws_size,
                              hipStream_t stream) {
    const float* x  = (const float*)d_in[0];
    const float* W1 = (const float*)d_in[1];
    const float* b1 = (const float*)d_in[2];
    const float* W2 = (const float*)d_in[3];
    const float* b2 = (const float*)d_in[4];
    float* out = (float*)d_out;

    unsigned short* xb   = (unsigned short*)d_ws;                 // MPAD*512
    unsigned short* W1T  = xb   + (size_t)MPAD * D_MODEL;         // 2048*512
    unsigned short* W2T  = W1T  + (size_t)NPAD * D_MODEL;         // 512*2048
    unsigned short* hT   = W2T  + (size_t)D_MODEL * NPAD;         // NPAD*MPAD (transposed)
    unsigned short* h2b  = hT   + (size_t)NPAD * MPAD;            // MPAD*NPAD
    unsigned short* img2 = h2b  + (size_t)MPAD * NPAD;            // 800*7524

    prep<<<dim3((MPAD * D_MODEL / 4 + 255) / 256, 1, 3), 256, 0, stream>>>(
        x, xb, W1, W1T, W2, W2T);

    // GEMM1: hT = (xb @ W1T^T + b1)^T   (bf16, transposed out), grid 16x113, 1024 thr
    gemm_bt<0><<<dim3(NPAD / 128, MPAD / 128), 1024, 0, stream>>>(
        xb, W1T, b1, hT, D_MODEL, D_MODEL, 0, HD, MPAD);

    fold_norm<<<dim3(HP, 100), 128, 0, stream>>>(hT, img2);
    unfold_k<<<dim3(400, 2), 256, 0, stream>>>(img2, h2b);

    // GEMM2: out = h2b @ W2T^T + b2  (fp32, rows<14400), grid 4x113, 1024 thr, K=1984
    gemm_bt<1><<<dim3(512 / 128, MPAD / 128), 1024, 0, stream>>>(
        h2b, W2T, b2, out, KEFF2, NPAD, D_MODEL, D_MODEL, MROWS);
}

// Round 23
// 161.955 us; speedup vs baseline: 1.1629x; 1.0192x over previous
//
#include <hip/hip_runtime.h>

// ---- problem geometry ----
#define D_MODEL 512
#define HD      1960
#define NPAD    2048          // HD padded to tile multiple
#define KEFF2   1984          // GEMM2 K loop bound: 31*64 (cols 1960..1983 zero-filled)
#define NVECS   720
#define MROWS   14400         // 4*3600
#define MPAD    14464         // 113*128
#define HP      66
#define WP      114
#define IMGPIX  7524          // HP*WP

typedef __bf16 bf16x8 __attribute__((ext_vector_type(8)));
typedef float  f32x4  __attribute__((ext_vector_type(4)));

__device__ __forceinline__ unsigned short f2bf(float f) {
    unsigned u = __builtin_bit_cast(unsigned, f);
    u += 0x7FFFu + ((u >> 16) & 1u);   // RNE
    return (unsigned short)(u >> 16);
}
__device__ __forceinline__ float bf2f(unsigned short s) {
    unsigned u = ((unsigned)s) << 16;
    return __builtin_bit_cast(float, u);
}

__device__ __forceinline__ void gload_lds16(const unsigned short* g, unsigned short* l) {
    __builtin_amdgcn_global_load_lds(
        (const __attribute__((address_space(1))) unsigned int*)g,
        (__attribute__((address_space(3))) unsigned int*)l,
        16, 0, 0);
}

// ---- fused prep: z=0 cvt x->bf16 (pad rows); z=1 W1->W1T; z=2 W2->W2T ----
__global__ void prep(const float* __restrict__ x,  unsigned short* __restrict__ xb,
                     const float* __restrict__ W1, unsigned short* __restrict__ W1T,
                     const float* __restrict__ W2, unsigned short* __restrict__ W2T) {
    const int z = blockIdx.z;
    const int t = threadIdx.x;
    if (z == 0) {
        size_t i = ((size_t)blockIdx.x * 256 + t) * 4;
        const size_t valid = (size_t)MROWS * D_MODEL;
        if (i >= (size_t)MPAD * D_MODEL) return;
        ushort4 o;
        if (i < valid) {
            float4 v = *(const float4*)(x + i);
            o.x = f2bf(v.x); o.y = f2bf(v.y); o.z = f2bf(v.z); o.w = f2bf(v.w);
        } else {
            o.x = o.y = o.z = o.w = 0;
        }
        *(ushort4*)(xb + i) = o;
        return;
    }
    __shared__ float tile[32][33];
    const int bid = blockIdx.x;
    if (bid >= 1024) return;
    const int tx = t & 31, ty = t >> 5;
    const float* src; unsigned short* dst;
    int srcR, srcC, dstR, dstC, c0, r0;
    if (z == 1) {  // W1 (512x1960) -> W1T (2048x512)
        src = W1; dst = W1T; srcR = 512; srcC = HD; dstR = NPAD; dstC = 512;
        c0 = (bid & 15) * 32; r0 = (bid >> 4) * 32;
    } else {       // W2 (1960x512) -> W2T (512x2048)
        src = W2; dst = W2T; srcR = HD; srcC = 512; dstR = 512; dstC = NPAD;
        c0 = (bid & 63) * 32; r0 = (bid >> 6) * 32;
    }
    #pragma unroll
    for (int i = 0; i < 32; i += 8) {
        int sr = c0 + ty + i, sc = r0 + tx;
        tile[ty + i][tx] = (sr < srcR && sc < srcC) ? src[(size_t)sr * srcC + sc] : 0.f;
    }
    __syncthreads();
    #pragma unroll
    for (int i = 0; i < 32; i += 8) {
        int dr = r0 + ty + i, dc = c0 + tx;
        if (dr < dstR && dc < dstC)
            dst[(size_t)dr * dstC + dc] = f2bf(tile[tx][ty + i]);
    }
}

// ---- 128x128 BK=64 dbuf counted-vmcnt bf16 GEMM, 16 waves, wave-tile 32x32 ----
// Wave grid: wr = wid>>2 (0..3, m), wc = wid&3 (0..3, n); acc 2x2.
// LDS amplification: A 4x, B 4x -> 128KB reads/block-K-tile (was 160KB at 16x64).
// LDS 64KB = 2 bufs x [A 16KB | B 16KB], slot-XOR (chunk kq at slot kq^(row&7)).
// Staging: 2 loads/thread/tile -> steady vmcnt(2), never 0 in-loop.
// lda = row stride; K = loop bound (K <= lda; tail cols must be zero).
// MODE 0: out bf16 TRANSPOSED hT[col*MPAD+row], skip cols >= validN (GEMM1)
// MODE 1: out fp32 row-major (ldc=512), skip rows >= validM          (GEMM2)
template<int MODE>
__global__ __launch_bounds__(1024, 8) void gemm_bt(const unsigned short* __restrict__ A,
                        const unsigned short* __restrict__ BT,
                        const float* __restrict__ bias,
                        void* __restrict__ Cout,
                        int K, int lda, int ldc, int validN, int validM) {
    __shared__ unsigned short lds[2][16384];   // 64KB total
    const int t    = threadIdx.x;
    const int wid  = t >> 6, lane = t & 63;
    const int wr   = wid >> 2, wc = wid & 3;
    const int lr   = lane & 15, lh = lane >> 4;
    const int m0   = blockIdx.y * 128, n0 = blockIdx.x * 128;

    // staging chunk map: 1024 chunks per matrix tile; thread owns chunk t of each
    const int rr = t >> 3;
    const int qq = (t & 7) ^ (rr & 7);

#define STAGE(buf, kt) do { \
        gload_lds16(A  + (size_t)(m0 + rr) * lda + (kt) + qq * 8, &lds[buf][0]    + t * 8); \
        gload_lds16(BT + (size_t)(n0 + rr) * lda + (kt) + qq * 8, &lds[buf][8192] + t * 8); \
    } while (0)

    f32x4 acc[2][2] = {};
    const int NT = K >> 6;

    STAGE(0, 0);
    for (int tt = 0; tt < NT; ++tt) {
        if (tt + 1 < NT) {
            STAGE((tt + 1) & 1, (tt + 1) * 64);
            asm volatile("s_waitcnt vmcnt(2)" ::: "memory");
        } else {
            asm volatile("s_waitcnt vmcnt(0)" ::: "memory");
        }
        __builtin_amdgcn_s_barrier();
        __builtin_amdgcn_sched_barrier(0);
        const unsigned short* La = &lds[tt & 1][0];
        const unsigned short* Lb = &lds[tt & 1][8192];
        #pragma unroll
        for (int ks = 0; ks < 2; ++ks) {
            const int sl = (ks * 4 + lh) ^ (lr & 7);
            bf16x8 a[2], b[2];
            #pragma unroll
            for (int f = 0; f < 2; ++f) {
                int row = wr * 32 + f * 16 + lr;       // row&7 == lr&7
                a[f] = *(const bf16x8*)(La + row * 64 + sl * 8);
            }
            #pragma unroll
            for (int g = 0; g < 2; ++g) {
                int row = wc * 32 + g * 16 + lr;
                b[g] = *(const bf16x8*)(Lb + row * 64 + sl * 8);
            }
            __builtin_amdgcn_s_setprio(1);
            #pragma unroll
            for (int fm = 0; fm < 2; ++fm)
                #pragma unroll
                for (int fn = 0; fn < 2; ++fn)
                    acc[fm][fn] = __builtin_amdgcn_mfma_f32_16x16x32_bf16(
                        a[fm], b[fn], acc[fm][fn], 0, 0, 0);
            __builtin_amdgcn_s_setprio(0);
        }
        __builtin_amdgcn_s_barrier();
        __builtin_amdgcn_sched_barrier(0);
    }
#undef STAGE

    // C/D layout: col=lane&15, row=(lane>>4)*4+j  [m89 verified]
    if (MODE == 0) {
        unsigned short* smem = &lds[0][0];   // 16384 ushorts = 32KB
        #pragma unroll
        for (int fm = 0; fm < 2; ++fm) {
            #pragma unroll
            for (int fn = 0; fn < 2; ++fn) {
                int lcol = wc * 32 + fn * 16 + lr;
                float bv = bias[n0 + lcol];
                #pragma unroll
                for (int j = 0; j < 4; ++j) {
                    int lrow = wr * 32 + fm * 16 + lh * 4 + j;
                    smem[lcol * 128 + (lrow ^ ((lcol & 15) << 3))] =
                        f2bf(acc[fm][fn][j] + bv);
                }
            }
        }
        __syncthreads();
        unsigned short* hT = (unsigned short*)Cout;
        int col = t >> 3, q = t & 7;     // 8 threads per column, 4 ushort4 each
        int gcol = n0 + col;
        if (gcol < validN) {
            #pragma unroll
            for (int r = 0; r < 4; ++r) {
                int row = q * 16 + r * 4;
                ushort4 v4 = *(const ushort4*)&smem[col * 128 + (row ^ ((col & 15) << 3))];
                *(ushort4*)&hT[(size_t)gcol * MPAD + m0 + row] = v4;
            }
        }
    } else {
        #pragma unroll
        for (int fm = 0; fm < 2; ++fm) {
            #pragma unroll
            for (int fn = 0; fn < 2; ++fn) {
                int gcol = n0 + wc * 32 + fn * 16 + lr;
                float bv = bias[gcol];
                #pragma unroll
                for (int j = 0; j < 4; ++j) {
                    int grow = m0 + wr * 32 + fm * 16 + lh * 4 + j;
                    if (grow < validM)
                        ((float*)Cout)[(size_t)grow * ldc + gcol] = acc[fm][fn][j] + bv;
                }
            }
        }
    }
}

// ---- fold + normalize + relu -> per-(b2,c) padded image (bf16), 8 ch/thread ----
__global__ void fold_norm(const unsigned short* __restrict__ hT, unsigned short* __restrict__ img2) {
    int y  = blockIdx.x;
    int g  = blockIdx.y;
    int b2 = g / 5, cg = g % 5;
    int c0 = cg * 8;
    int x  = threadIdx.x;
    if (x >= WP) return;
    float val[8] = {};
    if (y >= 3 && y < 63 && x >= 3 && x < 111) {
        int kiA[3], biA[3], nki = 0;
        for (int ki = y % 3; ki < 7; ki += 3) {
            int bi = (y - ki) / 3;
            if (y - ki >= 0 && bi < 20) { kiA[nki] = ki; biA[nki] = bi; ++nki; }
        }
        int kjA[3], bjA[3], nkj = 0;
        for (int kj = x % 3; kj < 7; kj += 3) {
            int bj = (x - kj) / 3;
            if (x - kj >= 0 && bj < 36) { kjA[nkj] = kj; bjA[nkj] = bj; ++nkj; }
        }
        float s[8] = {};
        for (int i = 0; i < nki; ++i) {
            for (int j = 0; j < nkj; ++j) {
                int row = b2 * NVECS + biA[i] * 36 + bjA[j];
                int colb = kiA[i] * 7 + kjA[j];
                #pragma unroll
                for (int q = 0; q < 8; ++q)
                    s[q] += bf2f(hT[(size_t)((c0 + q) * 49 + colb) * MPAD + row]);
            }
        }
        float inv = 1.f / (float)(nki * nkj);
        #pragma unroll
        for (int q = 0; q < 8; ++q)
            val[q] = fmaxf(s[q] * inv, 0.f);
    }
    #pragma unroll
    for (int q = 0; q < 8; ++q)
        img2[(size_t)(b2 * 40 + c0 + q) * IMGPIX + y * WP + x] = f2bf(val[q]);
}

// ---- unfold, LDS-staged ----
__global__ void unfold_k(const unsigned short* __restrict__ img2, unsigned short* __restrict__ h2b) {
    __shared__ unsigned short lds[20 * 798];
    __shared__ unsigned short lut[980];
    const int gb = blockIdx.x;                 // b2*20 + bi
    const int cg = blockIdx.y;
    const int b2 = gb / 20, bi = gb % 20;
    const int t  = threadIdx.x;

    const unsigned short* src = img2 + (size_t)(b2 * 40 + cg * 20) * IMGPIX + (bi * 3) * WP;
    for (int p = t; p < 7980; p += 256) {
        int cc = p / 399, rem2 = p - cc * 399;
        *(ushort2*)&lds[cc * 798 + rem2 * 2] =
            *(const ushort2*)&src[(size_t)cc * IMGPIX + rem2 * 2];
    }
    for (int L = t; L < 980; L += 256) {
        int cc = L / 49, kk = L - cc * 49;
        lut[L] = (unsigned short)(cc * 798 + (kk / 7) * 114 + (kk % 7));
    }
    __syncthreads();

    const int cpr   = (cg == 0) ? 245 : 267;
    const int total = 36 * cpr;
    const int rowbase = b2 * NVECS + bi * 36;
    const int hdbase  = cg * 980;
    for (int i = t; i < total; i += 256) {
        int r = i / cpr, q = i - r * cpr;
        int hl = q * 4;
        ushort4 v;
        unsigned short* vv = (unsigned short*)&v;
        #pragma unroll
        for (int e = 0; e < 4; ++e) {
            int h = hl + e;
            vv[e] = (h < 980) ? lds[lut[h] + r * 3] : (unsigned short)0;
        }
        *(ushort4*)&h2b[(size_t)(rowbase + r) * NPAD + hdbase + hl] = v;
    }
}

extern "C" void kernel_launch(void* const* d_in, const int* in_sizes, int n_in,
                              void* d_out, int out_size, void* d_ws, size_t ws_size,
                              hipStream_t stream) {
    const float* x  = (const float*)d_in[0];
    const float* W1 = (const float*)d_in[1];
    const float* b1 = (const float*)d_in[2];
    const float* W2 = (const float*)d_in[3];
    const float* b2 = (const float*)d_in[4];
    float* out = (float*)d_out;

    unsigned short* xb   = (unsigned short*)d_ws;                 // MPAD*512
    unsigned short* W1T  = xb   + (size_t)MPAD * D_MODEL;         // 2048*512
    unsigned short* W2T  = W1T  + (size_t)NPAD * D_MODEL;         // 512*2048
    unsigned short* hT   = W2T  + (size_t)D_MODEL * NPAD;         // NPAD*MPAD (transposed)
    unsigned short* h2b  = hT   + (size_t)NPAD * MPAD;            // MPAD*NPAD
    unsigned short* img2 = h2b  + (size_t)MPAD * NPAD;            // 800*7524

    prep<<<dim3((MPAD * D_MODEL / 4 + 255) / 256, 1, 3), 256, 0, stream>>>(
        x, xb, W1, W1T, W2, W2T);

    // GEMM1: hT = (xb @ W1T^T + b1)^T   (bf16, transposed out), grid 16x113, 1024 thr
    gemm_bt<0><<<dim3(NPAD / 128, MPAD / 128), 1024, 0, stream>>>(
        xb, W1T, b1, hT, D_MODEL, D_MODEL, 0, HD, MPAD);

    fold_norm<<<dim3(HP, 100), 128, 0, stream>>>(hT, img2);
    unfold_k<<<dim3(400, 2), 256, 0, stream>>>(img2, h2b);

    // GEMM2: out = h2b @ W2T^T + b2  (fp32, rows<14400), grid 4x113, 1024 thr, K=1984
    gemm_bt<1><<<dim3(512 / 128, MPAD / 128), 1024, 0, stream>>>(
        h2b, W2T, b2, out, KEFF2, NPAD, D_MODEL, D_MODEL, MROWS);
}

// Round 24
// 161.475 us; speedup vs baseline: 1.1664x; 1.0030x over previous
//
#include <hip/hip_runtime.h>

// ---- problem geometry ----
#define D_MODEL 512
#define HD      1960
#define NPAD    2048          // HD padded to tile multiple
#define KEFF2   1984          // GEMM2 K loop bound: 31*64 (cols 1960..1983 zero-filled)
#define NVECS   720
#define MROWS   14400         // 4*3600
#define MPAD    14464         // 113*128
#define HP      66
#define WP      114
#define IMGPIX  7524          // HP*WP

typedef __bf16 bf16x8 __attribute__((ext_vector_type(8)));
typedef float  f32x4  __attribute__((ext_vector_type(4)));

__device__ __forceinline__ unsigned short f2bf(float f) {
    unsigned u = __builtin_bit_cast(unsigned, f);
    u += 0x7FFFu + ((u >> 16) & 1u);   // RNE
    return (unsigned short)(u >> 16);
}
__device__ __forceinline__ float bf2f(unsigned short s) {
    unsigned u = ((unsigned)s) << 16;
    return __builtin_bit_cast(float, u);
}

__device__ __forceinline__ void gload_lds16(const unsigned short* g, unsigned short* l) {
    __builtin_amdgcn_global_load_lds(
        (const __attribute__((address_space(1))) unsigned int*)g,
        (__attribute__((address_space(3))) unsigned int*)l,
        16, 0, 0);
}

// ---- fused prep: z=0 cvt x->bf16 (pad rows); z=1 W1->W1T; z=2 W2->W2T ----
__global__ void prep(const float* __restrict__ x,  unsigned short* __restrict__ xb,
                     const float* __restrict__ W1, unsigned short* __restrict__ W1T,
                     const float* __restrict__ W2, unsigned short* __restrict__ W2T) {
    const int z = blockIdx.z;
    const int t = threadIdx.x;
    if (z == 0) {
        size_t i = ((size_t)blockIdx.x * 256 + t) * 4;
        const size_t valid = (size_t)MROWS * D_MODEL;
        if (i >= (size_t)MPAD * D_MODEL) return;
        ushort4 o;
        if (i < valid) {
            float4 v = *(const float4*)(x + i);
            o.x = f2bf(v.x); o.y = f2bf(v.y); o.z = f2bf(v.z); o.w = f2bf(v.w);
        } else {
            o.x = o.y = o.z = o.w = 0;
        }
        *(ushort4*)(xb + i) = o;
        return;
    }
    __shared__ float tile[32][33];
    const int bid = blockIdx.x;
    if (bid >= 1024) return;
    const int tx = t & 31, ty = t >> 5;
    const float* src; unsigned short* dst;
    int srcR, srcC, dstR, dstC, c0, r0;
    if (z == 1) {  // W1 (512x1960) -> W1T (2048x512)
        src = W1; dst = W1T; srcR = 512; srcC = HD; dstR = NPAD; dstC = 512;
        c0 = (bid & 15) * 32; r0 = (bid >> 4) * 32;
    } else {       // W2 (1960x512) -> W2T (512x2048)
        src = W2; dst = W2T; srcR = HD; srcC = 512; dstR = 512; dstC = NPAD;
        c0 = (bid & 63) * 32; r0 = (bid >> 6) * 32;
    }
    #pragma unroll
    for (int i = 0; i < 32; i += 8) {
        int sr = c0 + ty + i, sc = r0 + tx;
        tile[ty + i][tx] = (sr < srcR && sc < srcC) ? src[(size_t)sr * srcC + sc] : 0.f;
    }
    __syncthreads();
    #pragma unroll
    for (int i = 0; i < 32; i += 8) {
        int dr = r0 + ty + i, dc = c0 + tx;
        if (dr < dstR && dc < dstC)
            dst[(size_t)dr * dstC + dc] = f2bf(tile[tx][ty + i]);
    }
}

// ---- 128x128 BK=64 dbuf counted-vmcnt bf16 GEMM, 16 waves, wave-tile 32x32 ----
// R24 A/B: s_setprio pair REMOVED (m190: setprio hurts lockstep barrier-synced waves).
// Wave grid: wr = wid>>2 (0..3, m), wc = wid&3 (0..3, n); acc 2x2.
// LDS 64KB = 2 bufs x [A 16KB | B 16KB], slot-XOR (chunk kq at slot kq^(row&7)).
// Staging: 2 loads/thread/tile -> steady vmcnt(2), never 0 in-loop.
// lda = row stride; K = loop bound (K <= lda; tail cols must be zero).
// MODE 0: out bf16 TRANSPOSED hT[col*MPAD+row], skip cols >= validN (GEMM1)
// MODE 1: out fp32 row-major (ldc=512), skip rows >= validM          (GEMM2)
template<int MODE>
__global__ __launch_bounds__(1024, 8) void gemm_bt(const unsigned short* __restrict__ A,
                        const unsigned short* __restrict__ BT,
                        const float* __restrict__ bias,
                        void* __restrict__ Cout,
                        int K, int lda, int ldc, int validN, int validM) {
    __shared__ unsigned short lds[2][16384];   // 64KB total
    const int t    = threadIdx.x;
    const int wid  = t >> 6, lane = t & 63;
    const int wr   = wid >> 2, wc = wid & 3;
    const int lr   = lane & 15, lh = lane >> 4;
    const int m0   = blockIdx.y * 128, n0 = blockIdx.x * 128;

    // staging chunk map: 1024 chunks per matrix tile; thread owns chunk t of each
    const int rr = t >> 3;
    const int qq = (t & 7) ^ (rr & 7);

#define STAGE(buf, kt) do { \
        gload_lds16(A  + (size_t)(m0 + rr) * lda + (kt) + qq * 8, &lds[buf][0]    + t * 8); \
        gload_lds16(BT + (size_t)(n0 + rr) * lda + (kt) + qq * 8, &lds[buf][8192] + t * 8); \
    } while (0)

    f32x4 acc[2][2] = {};
    const int NT = K >> 6;

    STAGE(0, 0);
    for (int tt = 0; tt < NT; ++tt) {
        if (tt + 1 < NT) {
            STAGE((tt + 1) & 1, (tt + 1) * 64);
            asm volatile("s_waitcnt vmcnt(2)" ::: "memory");
        } else {
            asm volatile("s_waitcnt vmcnt(0)" ::: "memory");
        }
        __builtin_amdgcn_s_barrier();
        __builtin_amdgcn_sched_barrier(0);
        const unsigned short* La = &lds[tt & 1][0];
        const unsigned short* Lb = &lds[tt & 1][8192];
        #pragma unroll
        for (int ks = 0; ks < 2; ++ks) {
            const int sl = (ks * 4 + lh) ^ (lr & 7);
            bf16x8 a[2], b[2];
            #pragma unroll
            for (int f = 0; f < 2; ++f) {
                int row = wr * 32 + f * 16 + lr;       // row&7 == lr&7
                a[f] = *(const bf16x8*)(La + row * 64 + sl * 8);
            }
            #pragma unroll
            for (int g = 0; g < 2; ++g) {
                int row = wc * 32 + g * 16 + lr;
                b[g] = *(const bf16x8*)(Lb + row * 64 + sl * 8);
            }
            #pragma unroll
            for (int fm = 0; fm < 2; ++fm)
                #pragma unroll
                for (int fn = 0; fn < 2; ++fn)
                    acc[fm][fn] = __builtin_amdgcn_mfma_f32_16x16x32_bf16(
                        a[fm], b[fn], acc[fm][fn], 0, 0, 0);
        }
        __builtin_amdgcn_s_barrier();
        __builtin_amdgcn_sched_barrier(0);
    }
#undef STAGE

    // C/D layout: col=lane&15, row=(lane>>4)*4+j  [m89 verified]
    if (MODE == 0) {
        unsigned short* smem = &lds[0][0];   // 16384 ushorts = 32KB
        #pragma unroll
        for (int fm = 0; fm < 2; ++fm) {
            #pragma unroll
            for (int fn = 0; fn < 2; ++fn) {
                int lcol = wc * 32 + fn * 16 + lr;
                float bv = bias[n0 + lcol];
                #pragma unroll
                for (int j = 0; j < 4; ++j) {
                    int lrow = wr * 32 + fm * 16 + lh * 4 + j;
                    smem[lcol * 128 + (lrow ^ ((lcol & 15) << 3))] =
                        f2bf(acc[fm][fn][j] + bv);
                }
            }
        }
        __syncthreads();
        unsigned short* hT = (unsigned short*)Cout;
        int col = t >> 3, q = t & 7;     // 8 threads per column, 4 ushort4 each
        int gcol = n0 + col;
        if (gcol < validN) {
            #pragma unroll
            for (int r = 0; r < 4; ++r) {
                int row = q * 16 + r * 4;
                ushort4 v4 = *(const ushort4*)&smem[col * 128 + (row ^ ((col & 15) << 3))];
                *(ushort4*)&hT[(size_t)gcol * MPAD + m0 + row] = v4;
            }
        }
    } else {
        #pragma unroll
        for (int fm = 0; fm < 2; ++fm) {
            #pragma unroll
            for (int fn = 0; fn < 2; ++fn) {
                int gcol = n0 + wc * 32 + fn * 16 + lr;
                float bv = bias[gcol];
                #pragma unroll
                for (int j = 0; j < 4; ++j) {
                    int grow = m0 + wr * 32 + fm * 16 + lh * 4 + j;
                    if (grow < validM)
                        ((float*)Cout)[(size_t)grow * ldc + gcol] = acc[fm][fn][j] + bv;
                }
            }
        }
    }
}

// ---- fold + normalize + relu -> per-(b2,c) padded image (bf16), 8 ch/thread ----
__global__ void fold_norm(const unsigned short* __restrict__ hT, unsigned short* __restrict__ img2) {
    int y  = blockIdx.x;
    int g  = blockIdx.y;
    int b2 = g / 5, cg = g % 5;
    int c0 = cg * 8;
    int x  = threadIdx.x;
    if (x >= WP) return;
    float val[8] = {};
    if (y >= 3 && y < 63 && x >= 3 && x < 111) {
        int kiA[3], biA[3], nki = 0;
        for (int ki = y % 3; ki < 7; ki += 3) {
            int bi = (y - ki) / 3;
            if (y - ki >= 0 && bi < 20) { kiA[nki] = ki; biA[nki] = bi; ++nki; }
        }
        int kjA[3], bjA[3], nkj = 0;
        for (int kj = x % 3; kj < 7; kj += 3) {
            int bj = (x - kj) / 3;
            if (x - kj >= 0 && bj < 36) { kjA[nkj] = kj; bjA[nkj] = bj; ++nkj; }
        }
        float s[8] = {};
        for (int i = 0; i < nki; ++i) {
            for (int j = 0; j < nkj; ++j) {
                int row = b2 * NVECS + biA[i] * 36 + bjA[j];
                int colb = kiA[i] * 7 + kjA[j];
                #pragma unroll
                for (int q = 0; q < 8; ++q)
                    s[q] += bf2f(hT[(size_t)((c0 + q) * 49 + colb) * MPAD + row]);
            }
        }
        float inv = 1.f / (float)(nki * nkj);
        #pragma unroll
        for (int q = 0; q < 8; ++q)
            val[q] = fmaxf(s[q] * inv, 0.f);
    }
    #pragma unroll
    for (int q = 0; q < 8; ++q)
        img2[(size_t)(b2 * 40 + c0 + q) * IMGPIX + y * WP + x] = f2bf(val[q]);
}

// ---- unfold, LDS-staged ----
__global__ void unfold_k(const unsigned short* __restrict__ img2, unsigned short* __restrict__ h2b) {
    __shared__ unsigned short lds[20 * 798];
    __shared__ unsigned short lut[980];
    const int gb = blockIdx.x;                 // b2*20 + bi
    const int cg = blockIdx.y;
    const int b2 = gb / 20, bi = gb % 20;
    const int t  = threadIdx.x;

    const unsigned short* src = img2 + (size_t)(b2 * 40 + cg * 20) * IMGPIX + (bi * 3) * WP;
    for (int p = t; p < 7980; p += 256) {
        int cc = p / 399, rem2 = p - cc * 399;
        *(ushort2*)&lds[cc * 798 + rem2 * 2] =
            *(const ushort2*)&src[(size_t)cc * IMGPIX + rem2 * 2];
    }
    for (int L = t; L < 980; L += 256) {
        int cc = L / 49, kk = L - cc * 49;
        lut[L] = (unsigned short)(cc * 798 + (kk / 7) * 114 + (kk % 7));
    }
    __syncthreads();

    const int cpr   = (cg == 0) ? 245 : 267;
    const int total = 36 * cpr;
    const int rowbase = b2 * NVECS + bi * 36;
    const int hdbase  = cg * 980;
    for (int i = t; i < total; i += 256) {
        int r = i / cpr, q = i - r * cpr;
        int hl = q * 4;
        ushort4 v;
        unsigned short* vv = (unsigned short*)&v;
        #pragma unroll
        for (int e = 0; e < 4; ++e) {
            int h = hl + e;
            vv[e] = (h < 980) ? lds[lut[h] + r * 3] : (unsigned short)0;
        }
        *(ushort4*)&h2b[(size_t)(rowbase + r) * NPAD + hdbase + hl] = v;
    }
}

extern "C" void kernel_launch(void* const* d_in, const int* in_sizes, int n_in,
                              void* d_out, int out_size, void* d_ws, size_t ws_size,
                              hipStream_t stream) {
    const float* x  = (const float*)d_in[0];
    const float* W1 = (const float*)d_in[1];
    const float* b1 = (const float*)d_in[2];
    const float* W2 = (const float*)d_in[3];
    const float* b2 = (const float*)d_in[4];
    float* out = (float*)d_out;

    unsigned short* xb   = (unsigned short*)d_ws;                 // MPAD*512
    unsigned short* W1T  = xb   + (size_t)MPAD * D_MODEL;         // 2048*512
    unsigned short* W2T  = W1T  + (size_t)NPAD * D_MODEL;         // 512*2048
    unsigned short* hT   = W2T  + (size_t)D_MODEL * NPAD;         // NPAD*MPAD (transposed)
    unsigned short* h2b  = hT   + (size_t)NPAD * MPAD;            // MPAD*NPAD
    unsigned short* img2 = h2b  + (size_t)MPAD * NPAD;            // 800*7524

    prep<<<dim3((MPAD * D_MODEL / 4 + 255) / 256, 1, 3), 256, 0, stream>>>(
        x, xb, W1, W1T, W2, W2T);

    // GEMM1: hT = (xb @ W1T^T + b1)^T   (bf16, transposed out), grid 16x113, 1024 thr
    gemm_bt<0><<<dim3(NPAD / 128, MPAD / 128), 1024, 0, stream>>>(
        xb, W1T, b1, hT, D_MODEL, D_MODEL, 0, HD, MPAD);

    fold_norm<<<dim3(HP, 100), 128, 0, stream>>>(hT, img2);
    unfold_k<<<dim3(400, 2), 256, 0, stream>>>(img2, h2b);

    // GEMM2: out = h2b @ W2T^T + b2  (fp32, rows<14400), grid 4x113, 1024 thr, K=1984
    gemm_bt<1><<<dim3(512 / 128, MPAD / 128), 1024, 0, stream>>>(
        h2b, W2T, b2, out, KEFF2, NPAD, D_MODEL, D_MODEL, MROWS);
}